// Round 1
// baseline (1701.400 us; speedup 1.0000x reference)
//
#include <hip/hip_runtime.h>
#include <cstdint>
#include <cstddef>

// ---------------------------------------------------------------------------
// Types
// ---------------------------------------------------------------------------
using bf16x8 = __attribute__((ext_vector_type(8))) short;
using f32x4  = __attribute__((ext_vector_type(4))) float;

__device__ __forceinline__ unsigned short f2bf(float f) {
  unsigned int u = __builtin_bit_cast(unsigned int, f);
  u += 0x7fffu + ((u >> 16) & 1u);
  return (unsigned short)(u >> 16);
}

// async global->LDS 16B per lane. LDS dest must be wave-uniform-base + lane*16,
// which our t*16 layout satisfies.
__device__ __forceinline__ void async_cp16(const void* g, void* l) {
  __builtin_amdgcn_global_load_lds(
      (__attribute__((address_space(1))) void*)(g),
      (__attribute__((address_space(3))) void*)(l), 16, 0, 0);
}

// ---------------------------------------------------------------------------
// Epilogue params
// ---------------------------------------------------------------------------
struct EpParams {
  const float* bias;    // col bias
  const float* bias2;   // (qkv) k bias
  const float* bias3;   // (qkv) v bias
  const float* res;     // residual fp32 [M][ldC]
  float* outf;          // fp32 out
  unsigned short* outb; // bf16 out
  unsigned short* outb2;
  unsigned short* outb3;
  long long strideCz;
  int ldC;
  int pair_base;
};

// EP: 0=QKV scatter, 1=scores f32, 2=ctx scatter, 3=bias+residual f32, 4=gelu bf16
template <int BM, int BN, int WGM, int WGN, int FI, int FJ, int EP>
__global__ __launch_bounds__(256, 2) void gemm_bt(
    const unsigned short* __restrict__ A, const unsigned short* __restrict__ B,
    int K, int kTiles, long long strideAz, long long strideBz, EpParams p) {
  __shared__ alignas(16) unsigned short As[BM * 64];
  __shared__ alignas(16) unsigned short Bs[BN * 64];
  const int t = threadIdx.x;
  const int lane = t & 63;
  const int w = t >> 6;
  const int wr = w / WGN, wc = w % WGN;
  const int lm = lane & 15, quad = lane >> 4;
  const int m0 = blockIdx.y * BM, n0 = blockIdx.x * BN;
  const int bz = blockIdx.z;
  A += (long long)bz * strideAz;
  B += (long long)bz * strideBz;

  f32x4 acc[FI][FJ] = {};

  const int rowA = t >> 3;         // 0..31 (row within a 32-row staging step)
  const int colOff = (t & 7) * 8;  // bf16 elems within BK=64

  for (int kt = 0; kt < kTiles; ++kt) {
    const unsigned short* ga = A + (size_t)(m0 + rowA) * K + kt * 64 + colOff;
    const unsigned short* gb = B + (size_t)(n0 + rowA) * K + kt * 64 + colOff;
#pragma unroll
    for (int s = 0; s < BM / 32; ++s)
      async_cp16(ga + (size_t)s * 32 * K, &As[s * 2048 + t * 8]);
#pragma unroll
    for (int s = 0; s < BN / 32; ++s)
      async_cp16(gb + (size_t)s * 32 * K, &Bs[s * 2048 + t * 8]);
    __syncthreads();
#pragma unroll
    for (int ks = 0; ks < 2; ++ks) {
      bf16x8 af[FI], bfr[FJ];
#pragma unroll
      for (int i = 0; i < FI; ++i)
        af[i] = *(const bf16x8*)&As[(wr * FI * 16 + i * 16 + lm) * 64 + ks * 32 + quad * 8];
#pragma unroll
      for (int j = 0; j < FJ; ++j)
        bfr[j] = *(const bf16x8*)&Bs[(wc * FJ * 16 + j * 16 + lm) * 64 + ks * 32 + quad * 8];
#pragma unroll
      for (int i = 0; i < FI; ++i)
#pragma unroll
        for (int j = 0; j < FJ; ++j)
          acc[i][j] = __builtin_amdgcn_mfma_f32_16x16x32_bf16(af[i], bfr[j], acc[i][j], 0, 0, 0);
    }
    __syncthreads();
  }

  float* outf = p.outf ? p.outf + (long long)bz * p.strideCz : (float*)nullptr;
#pragma unroll
  for (int i = 0; i < FI; ++i) {
#pragma unroll
    for (int j = 0; j < FJ; ++j) {
#pragma unroll
      for (int r = 0; r < 4; ++r) {
        int row = m0 + wr * FI * 16 + i * 16 + quad * 4 + r;
        int col = n0 + wc * FJ * 16 + j * 16 + lm;
        float v = acc[i][j][r];
        if constexpr (EP == 1) {
          outf[((size_t)row << 10) + col] = v;
        } else if constexpr (EP == 0) {
          int bb = row >> 10, s = row & 1023;
          if (col < 1024) {
            float q = (v + p.bias[col]) * 0.125f;
            int hd = col >> 6, dh = col & 63;
            p.outb[((size_t)(bb * 16 + hd) << 16) + (s << 6) + dh] = f2bf(q);
          } else if (col < 2048) {
            int c2 = col - 1024;
            float kk = v + p.bias2[c2];
            int hd = c2 >> 6, dh = c2 & 63;
            p.outb2[((size_t)(bb * 16 + hd) << 16) + (s << 6) + dh] = f2bf(kk);
          } else {
            int c3 = col - 2048;
            float vv = v + p.bias3[c3];
            int hd = c3 >> 6, dh = c3 & 63;
            p.outb3[((size_t)(bb * 16 + hd) << 16) + ((size_t)dh << 10) + s] = f2bf(vv);
          }
        } else if constexpr (EP == 2) {
          int pair = p.pair_base + bz;
          int bb = pair >> 4, hd = pair & 15;
          p.outb[((size_t)bb << 20) + ((size_t)row << 10) + (hd << 6) + col] = f2bf(v);
        } else if constexpr (EP == 3) {
          size_t idx = (size_t)row * p.ldC + col;
          outf[idx] = v + p.bias[col] + p.res[idx];
        } else if constexpr (EP == 4) {
          float val = v + p.bias[col];
          float g = 0.5f * val * (1.0f + erff(val * 0.70710678118654752f));
          p.outb[(size_t)row * p.ldC + col] = f2bf(g);
        }
      }
    }
  }
}

// ---------------------------------------------------------------------------
// Weight convert + transpose: fp32 [K][N] -> bf16 [N][K]  (BT layout)
// One layer per launch; 6 matrices (Wq,Wk,Wv -> wqkv concat; Wo; W1; W2)
// ---------------------------------------------------------------------------
__global__ __launch_bounds__(256) void transpose_w(
    const float* __restrict__ Wq, const float* __restrict__ Wk,
    const float* __restrict__ Wv, const float* __restrict__ Wo,
    const float* __restrict__ W1, const float* __restrict__ W2,
    unsigned short* __restrict__ wqkv, unsigned short* __restrict__ wo,
    unsigned short* __restrict__ w1, unsigned short* __restrict__ w2) {
  int blk = blockIdx.x;
  int kind, local;
  if (blk < 1024) { kind = blk >> 8; local = blk & 255; }
  else if (blk < 2048) { kind = 4; local = blk - 1024; }
  else { kind = 5; local = blk - 2048; }
  const float* src;
  unsigned short* dst;
  int K, N;
  switch (kind) {
    case 0: src = Wq; dst = wqkv;                  K = 1024; N = 1024; break;
    case 1: src = Wk; dst = wqkv + 1024 * 1024;    K = 1024; N = 1024; break;
    case 2: src = Wv; dst = wqkv + 2048 * 1024;    K = 1024; N = 1024; break;
    case 3: src = Wo; dst = wo;                    K = 1024; N = 1024; break;
    case 4: src = W1; dst = w1;                    K = 1024; N = 4096; break;
    default: src = W2; dst = w2;                   K = 4096; N = 1024; break;
  }
  int tilesK = K >> 6;
  int tk = local % tilesK, tn = local / tilesK;
  int k0 = tk << 6, n0 = tn << 6;
  __shared__ float lds[64][65];
  int t = threadIdx.x;
  int rr = t >> 4, cc = (t & 15) * 4;
#pragma unroll
  for (int pp = 0; pp < 4; ++pp) {
    float4 v = *(const float4*)&src[(size_t)(k0 + rr + pp * 16) * N + n0 + cc];
    lds[rr + pp * 16][cc + 0] = v.x;
    lds[rr + pp * 16][cc + 1] = v.y;
    lds[rr + pp * 16][cc + 2] = v.z;
    lds[rr + pp * 16][cc + 3] = v.w;
  }
  __syncthreads();
#pragma unroll
  for (int pp = 0; pp < 4; ++pp) {
    int nr = rr + pp * 16;
    ushort4 o;
    o.x = f2bf(lds[cc + 0][nr]);
    o.y = f2bf(lds[cc + 1][nr]);
    o.z = f2bf(lds[cc + 2][nr]);
    o.w = f2bf(lds[cc + 3][nr]);
    *(ushort4*)&dst[(size_t)(n0 + nr) * K + k0 + cc] = o;
  }
}

// ---------------------------------------------------------------------------
// fp32 -> bf16 elementwise
// ---------------------------------------------------------------------------
__global__ __launch_bounds__(256) void cvt_bf16(const float* __restrict__ in,
                                                unsigned short* __restrict__ out) {
  int i = (blockIdx.x * 256 + threadIdx.x) * 4;
  float4 v = *(const float4*)&in[i];
  ushort4 o;
  o.x = f2bf(v.x); o.y = f2bf(v.y); o.z = f2bf(v.z); o.w = f2bf(v.w);
  *(ushort4*)&out[i] = o;
}

// ---------------------------------------------------------------------------
// Row softmax over S=1024 with attention mask; fp32 in, bf16 out
// ---------------------------------------------------------------------------
__global__ __launch_bounds__(256) void softmax_k(const float* __restrict__ Sc,
                                                 const int* __restrict__ mask,
                                                 unsigned short* __restrict__ P,
                                                 int pair_base) {
  int rowid = blockIdx.x;
  int z = rowid >> 10;
  int q = rowid & 1023;
  int pair = pair_base + z;
  int bb = pair >> 4;
  const float* srow = Sc + ((size_t)z << 20) + ((size_t)q << 10);
  const int* mrow = mask + (bb << 10);
  int t = threadIdx.x;
  float4 s4 = *(const float4*)&srow[t * 4];
  int4 m4 = *(const int4*)&mrow[t * 4];
  float v0 = m4.x ? s4.x : -1e30f;
  float v1 = m4.y ? s4.y : -1e30f;
  float v2 = m4.z ? s4.z : -1e30f;
  float v3 = m4.w ? s4.w : -1e30f;
  float mx = fmaxf(fmaxf(v0, v1), fmaxf(v2, v3));
  for (int o = 32; o > 0; o >>= 1) mx = fmaxf(mx, __shfl_xor(mx, o));
  __shared__ float red[4];
  __shared__ float red2[4];
  if ((t & 63) == 0) red[t >> 6] = mx;
  __syncthreads();
  mx = fmaxf(fmaxf(red[0], red[1]), fmaxf(red[2], red[3]));
  float e0 = (v0 > -1e29f) ? __expf(v0 - mx) : 0.f;
  float e1 = (v1 > -1e29f) ? __expf(v1 - mx) : 0.f;
  float e2 = (v2 > -1e29f) ? __expf(v2 - mx) : 0.f;
  float e3 = (v3 > -1e29f) ? __expf(v3 - mx) : 0.f;
  float sum = e0 + e1 + e2 + e3;
  for (int o = 32; o > 0; o >>= 1) sum += __shfl_xor(sum, o);
  if ((t & 63) == 0) red2[t >> 6] = sum;
  __syncthreads();
  sum = red2[0] + red2[1] + red2[2] + red2[3];
  float inv = 1.0f / sum;
  ushort4 o4;
  o4.x = f2bf(e0 * inv); o4.y = f2bf(e1 * inv);
  o4.z = f2bf(e2 * inv); o4.w = f2bf(e3 * inv);
  *(ushort4*)&P[((size_t)z << 20) + ((size_t)q << 10) + t * 4] = o4;
}

// ---------------------------------------------------------------------------
// LayerNorm over D=1024; writes fp32 + bf16 copies
// ---------------------------------------------------------------------------
__global__ __launch_bounds__(256) void ln_k(const float* __restrict__ in,
                                            const float* __restrict__ g,
                                            const float* __restrict__ b,
                                            float* __restrict__ outf,
                                            unsigned short* __restrict__ outb) {
  int row = blockIdx.x;
  int t = threadIdx.x;
  const float* x = in + ((size_t)row << 10);
  float4 v = *(const float4*)&x[t * 4];
  float s1 = v.x + v.y + v.z + v.w;
  float s2 = v.x * v.x + v.y * v.y + v.z * v.z + v.w * v.w;
  for (int o = 32; o > 0; o >>= 1) {
    s1 += __shfl_xor(s1, o);
    s2 += __shfl_xor(s2, o);
  }
  __shared__ float r1[4], r2[4];
  if ((t & 63) == 0) { r1[t >> 6] = s1; r2[t >> 6] = s2; }
  __syncthreads();
  s1 = r1[0] + r1[1] + r1[2] + r1[3];
  s2 = r2[0] + r2[1] + r2[2] + r2[3];
  float mean = s1 * (1.0f / 1024.0f);
  float var = s2 * (1.0f / 1024.0f) - mean * mean;
  float rstd = rsqrtf(var + 1e-12f);
  float4 gg = *(const float4*)&g[t * 4];
  float4 bb = *(const float4*)&b[t * 4];
  float o0 = (v.x - mean) * rstd * gg.x + bb.x;
  float o1 = (v.y - mean) * rstd * gg.y + bb.y;
  float o2 = (v.z - mean) * rstd * gg.z + bb.z;
  float o3 = (v.w - mean) * rstd * gg.w + bb.w;
  float4 of = make_float4(o0, o1, o2, o3);
  *(float4*)&outf[((size_t)row << 10) + t * 4] = of;
  ushort4 ob;
  ob.x = f2bf(o0); ob.y = f2bf(o1); ob.z = f2bf(o2); ob.w = f2bf(o3);
  *(ushort4*)&outb[((size_t)row << 10) + t * 4] = ob;
}

// ---------------------------------------------------------------------------
// Host driver
// ---------------------------------------------------------------------------
extern "C" void kernel_launch(void* const* d_in, const int* in_sizes, int n_in,
                              void* d_out, int out_size, void* d_ws, size_t ws_size,
                              hipStream_t stream) {
  (void)in_sizes; (void)n_in; (void)out_size; (void)ws_size;
  const float* x    = (const float*)d_in[0];
  const int*   mask = (const int*)d_in[1];
  const float* Wq   = (const float*)d_in[2];
  const float* bq   = (const float*)d_in[3];
  const float* Wk   = (const float*)d_in[4];
  const float* bk   = (const float*)d_in[5];
  const float* Wv   = (const float*)d_in[6];
  const float* bv   = (const float*)d_in[7];
  const float* Wo   = (const float*)d_in[8];
  const float* bo   = (const float*)d_in[9];
  const float* ln1g = (const float*)d_in[10];
  const float* ln1b = (const float*)d_in[11];
  const float* W1   = (const float*)d_in[12];
  const float* b1   = (const float*)d_in[13];
  const float* W2   = (const float*)d_in[14];
  const float* b2   = (const float*)d_in[15];
  const float* ln2g = (const float*)d_in[16];
  const float* ln2b = (const float*)d_in[17];
  float* out = (float*)d_out;

  char* wsp = (char*)d_ws;
  auto take = [&](size_t bytes) { char* r = wsp; wsp += bytes; return r; };
  unsigned short* wqkv = (unsigned short*)take(3072ull * 1024 * 2);
  unsigned short* wo_t = (unsigned short*)take(1024ull * 1024 * 2);
  unsigned short* w1_t = (unsigned short*)take(4096ull * 1024 * 2);
  unsigned short* w2_t = (unsigned short*)take(1024ull * 4096 * 2);
  float*          h    = (float*)take(2048ull * 1024 * 4);
  unsigned short* hbf  = (unsigned short*)take(2048ull * 1024 * 2);
  unsigned short* Qb   = (unsigned short*)take(2048ull * 1024 * 2);
  unsigned short* Kbuf = (unsigned short*)take(2048ull * 1024 * 2);
  unsigned short* VTb  = (unsigned short*)take(2048ull * 1024 * 2);
  unsigned short* ctxb = (unsigned short*)take(2048ull * 1024 * 2);
  unsigned short* ffb  = (unsigned short*)take(2048ull * 4096 * 2);
  float*          tmp  = (float*)take(2048ull * 1024 * 4);
  float*          scr  = (float*)take(8ull * 1024 * 1024 * 4);
  unsigned short* Pb   = (unsigned short*)take(8ull * 1024 * 1024 * 2);

  cvt_bf16<<<2048, 256, 0, stream>>>(x, hbf);

  for (int l = 0; l < 4; ++l) {
    transpose_w<<<3072, 256, 0, stream>>>(
        Wq + (size_t)l * 1048576, Wk + (size_t)l * 1048576,
        Wv + (size_t)l * 1048576, Wo + (size_t)l * 1048576,
        W1 + (size_t)l * 4194304, W2 + (size_t)l * 4194304,
        wqkv, wo_t, w1_t, w2_t);

    // QKV projection: [2048 x 3072] = hbf [2048x1024] * wqkv^T
    {
      EpParams p{};
      p.bias = bq + l * 1024; p.bias2 = bk + l * 1024; p.bias3 = bv + l * 1024;
      p.outb = Qb; p.outb2 = Kbuf; p.outb3 = VTb;
      gemm_bt<128, 128, 2, 2, 4, 4, 0><<<dim3(24, 16, 1), 256, 0, stream>>>(
          hbf, wqkv, 1024, 16, 0, 0, p);
    }

    // Attention in 4 chunks of 8 (b,h) pairs
    for (int c = 0; c < 4; ++c) {
      {
        EpParams p{};
        p.outf = scr; p.strideCz = 1048576;
        gemm_bt<128, 128, 2, 2, 4, 4, 1><<<dim3(8, 8, 8), 256, 0, stream>>>(
            Qb + (size_t)c * 8 * 65536, Kbuf + (size_t)c * 8 * 65536,
            64, 1, 65536, 65536, p);
      }
      softmax_k<<<8192, 256, 0, stream>>>(scr, mask, Pb, c * 8);
      {
        EpParams p{};
        p.outb = ctxb; p.pair_base = c * 8;
        gemm_bt<128, 64, 2, 2, 4, 2, 2><<<dim3(1, 8, 8), 256, 0, stream>>>(
            Pb, VTb + (size_t)c * 8 * 65536, 1024, 16, 1048576, 65536, p);
      }
    }

    // O projection + bias + residual
    {
      EpParams p{};
      p.bias = bo + l * 1024; p.res = (l == 0 ? x : h); p.outf = tmp; p.ldC = 1024;
      gemm_bt<128, 128, 2, 2, 4, 4, 3><<<dim3(8, 16, 1), 256, 0, stream>>>(
          ctxb, wo_t, 1024, 16, 0, 0, p);
    }
    ln_k<<<2048, 256, 0, stream>>>(tmp, ln1g + l * 1024, ln1b + l * 1024, h, hbf);

    // FFN1 + GELU
    {
      EpParams p{};
      p.bias = b1 + l * 4096; p.outb = ffb; p.ldC = 4096;
      gemm_bt<128, 128, 2, 2, 4, 4, 4><<<dim3(32, 16, 1), 256, 0, stream>>>(
          hbf, w1_t, 1024, 16, 0, 0, p);
    }
    // FFN2 + bias + residual
    {
      EpParams p{};
      p.bias = b2 + l * 1024; p.res = h; p.outf = tmp; p.ldC = 1024;
      gemm_bt<128, 128, 2, 2, 4, 4, 3><<<dim3(8, 16, 1), 256, 0, stream>>>(
          ffb, w2_t, 4096, 64, 0, 0, p);
    }
    ln_k<<<2048, 256, 0, stream>>>(tmp, ln2g + l * 1024, ln2b + l * 1024,
                                   (l == 3 ? out : h), hbf);
  }
}

// Round 2
// 1147.325 us; speedup vs baseline: 1.4829x; 1.4829x over previous
//
#include <hip/hip_runtime.h>
#include <cstdint>
#include <cstddef>

// ---------------------------------------------------------------------------
// Types
// ---------------------------------------------------------------------------
using bf16x8 = __attribute__((ext_vector_type(8))) short;
using f32x4  = __attribute__((ext_vector_type(4))) float;

__device__ __forceinline__ unsigned short f2bf(float f) {
  unsigned int u = __builtin_bit_cast(unsigned int, f);
  u += 0x7fffu + ((u >> 16) & 1u);
  return (unsigned short)(u >> 16);
}
__device__ __forceinline__ float bf2f(unsigned short h) {
  unsigned int u = ((unsigned int)h) << 16;
  return __builtin_bit_cast(float, u);
}

// async global->LDS 16B per lane. LDS dest must be wave-uniform-base + lane*16.
__device__ __forceinline__ void async_cp16(const void* g, void* l) {
  __builtin_amdgcn_global_load_lds(
      (__attribute__((address_space(1))) void*)(g),
      (__attribute__((address_space(3))) void*)(l), 16, 0, 0);
}

// ---------------------------------------------------------------------------
// Epilogue params
// ---------------------------------------------------------------------------
struct EpParams {
  const float* bias;    // col bias
  const float* bias2;   // (qkv) k bias
  const float* bias3;   // (qkv) v bias
  const float* res;     // residual fp32 [M][ldC]
  float* outf;          // fp32 out
  unsigned short* outb; // bf16 out
  unsigned short* outb2;
  unsigned short* outb3;
  long long strideCz;   // elements (bf16 out for EP=1)
  int ldC;
  int pair_base;
};

// EP: 0=QKV scatter, 1=scores bf16, 2=ctx scatter, 3=bias+residual f32, 4=gelu bf16
// LDS XOR swizzle: LDS slot (row, chunk) holds global 16B-chunk (chunk ^ (row&7))
// of that row; staging picks the source chunk per-lane, reads un-swizzle.
template <int BM, int BN, int WGM, int WGN, int FI, int FJ, int EP>
__global__ __launch_bounds__(256, 2) void gemm_bt(
    const unsigned short* __restrict__ A, const unsigned short* __restrict__ B,
    int K, int kTiles, long long strideAz, long long strideBz, EpParams p) {
  __shared__ alignas(16) unsigned short As[BM * 64];
  __shared__ alignas(16) unsigned short Bs[BN * 64];
  const int t = threadIdx.x;
  const int lane = t & 63;
  const int w = t >> 6;
  const int wr = w / WGN, wc = w % WGN;
  const int lm = lane & 15, quad = lane >> 4;
  const int m0 = blockIdx.y * BM, n0 = blockIdx.x * BN;
  const int bz = blockIdx.z;
  A += (long long)bz * strideAz;
  B += (long long)bz * strideBz;

  f32x4 acc[FI][FJ] = {};

  const int rowA = t >> 3;                       // 0..31 within a staging step
  const int colSw = ((t & 7) ^ (rowA & 7)) * 8;  // swizzled source column

  for (int kt = 0; kt < kTiles; ++kt) {
    const unsigned short* ga = A + (size_t)(m0 + rowA) * K + kt * 64 + colSw;
    const unsigned short* gb = B + (size_t)(n0 + rowA) * K + kt * 64 + colSw;
#pragma unroll
    for (int s = 0; s < BM / 32; ++s)
      async_cp16(ga + (size_t)s * 32 * K, &As[s * 2048 + t * 8]);
#pragma unroll
    for (int s = 0; s < BN / 32; ++s)
      async_cp16(gb + (size_t)s * 32 * K, &Bs[s * 2048 + t * 8]);
    __syncthreads();
#pragma unroll
    for (int ks = 0; ks < 2; ++ks) {
      bf16x8 af[FI], bfr[FJ];
#pragma unroll
      for (int i = 0; i < FI; ++i) {
        int ra = wr * FI * 16 + i * 16 + lm;
        af[i] = *(const bf16x8*)&As[ra * 64 + (((ks * 4 + quad) ^ (ra & 7)) << 3)];
      }
#pragma unroll
      for (int j = 0; j < FJ; ++j) {
        int rb = wc * FJ * 16 + j * 16 + lm;
        bfr[j] = *(const bf16x8*)&Bs[rb * 64 + (((ks * 4 + quad) ^ (rb & 7)) << 3)];
      }
#pragma unroll
      for (int i = 0; i < FI; ++i)
#pragma unroll
        for (int j = 0; j < FJ; ++j)
          acc[i][j] = __builtin_amdgcn_mfma_f32_16x16x32_bf16(af[i], bfr[j], acc[i][j], 0, 0, 0);
    }
    __syncthreads();
  }

#pragma unroll
  for (int i = 0; i < FI; ++i) {
#pragma unroll
    for (int j = 0; j < FJ; ++j) {
#pragma unroll
      for (int r = 0; r < 4; ++r) {
        int row = m0 + wr * FI * 16 + i * 16 + quad * 4 + r;
        int col = n0 + wc * FJ * 16 + j * 16 + lm;
        float v = acc[i][j][r];
        if constexpr (EP == 1) {
          p.outb[(long long)bz * p.strideCz + ((size_t)row << 10) + col] = f2bf(v);
        } else if constexpr (EP == 0) {
          int bb = row >> 10, s = row & 1023;
          if (col < 1024) {
            float q = (v + p.bias[col]) * 0.125f;
            int hd = col >> 6, dh = col & 63;
            p.outb[((size_t)(bb * 16 + hd) << 16) + (s << 6) + dh] = f2bf(q);
          } else if (col < 2048) {
            int c2 = col - 1024;
            float kk = v + p.bias2[c2];
            int hd = c2 >> 6, dh = c2 & 63;
            p.outb2[((size_t)(bb * 16 + hd) << 16) + (s << 6) + dh] = f2bf(kk);
          } else {
            int c3 = col - 2048;
            float vv = v + p.bias3[c3];
            int hd = c3 >> 6, dh = c3 & 63;
            p.outb3[((size_t)(bb * 16 + hd) << 16) + ((size_t)dh << 10) + s] = f2bf(vv);
          }
        } else if constexpr (EP == 2) {
          int pair = p.pair_base + bz;
          int bb = pair >> 4, hd = pair & 15;
          p.outb[((size_t)bb << 20) + ((size_t)row << 10) + (hd << 6) + col] = f2bf(v);
        } else if constexpr (EP == 3) {
          size_t idx = (size_t)row * p.ldC + col;
          p.outf[idx] = v + p.bias[col] + p.res[idx];
        } else if constexpr (EP == 4) {
          float val = v + p.bias[col];
          float g = 0.5f * val * (1.0f + erff(val * 0.70710678118654752f));
          p.outb[(size_t)row * p.ldC + col] = f2bf(g);
        }
      }
    }
  }
}

// ---------------------------------------------------------------------------
// Weight convert + transpose: fp32 [K][N] -> bf16 [N][K]  (BT layout)
// ---------------------------------------------------------------------------
__global__ __launch_bounds__(256) void transpose_w(
    const float* __restrict__ Wq, const float* __restrict__ Wk,
    const float* __restrict__ Wv, const float* __restrict__ Wo,
    const float* __restrict__ W1, const float* __restrict__ W2,
    unsigned short* __restrict__ wqkv, unsigned short* __restrict__ wo,
    unsigned short* __restrict__ w1, unsigned short* __restrict__ w2) {
  int blk = blockIdx.x;
  int kind, local;
  if (blk < 1024) { kind = blk >> 8; local = blk & 255; }
  else if (blk < 2048) { kind = 4; local = blk - 1024; }
  else { kind = 5; local = blk - 2048; }
  const float* src;
  unsigned short* dst;
  int K, N;
  switch (kind) {
    case 0: src = Wq; dst = wqkv;                  K = 1024; N = 1024; break;
    case 1: src = Wk; dst = wqkv + 1024 * 1024;    K = 1024; N = 1024; break;
    case 2: src = Wv; dst = wqkv + 2048 * 1024;    K = 1024; N = 1024; break;
    case 3: src = Wo; dst = wo;                    K = 1024; N = 1024; break;
    case 4: src = W1; dst = w1;                    K = 1024; N = 4096; break;
    default: src = W2; dst = w2;                   K = 4096; N = 1024; break;
  }
  int tilesK = K >> 6;
  int tk = local % tilesK, tn = local / tilesK;
  int k0 = tk << 6, n0 = tn << 6;
  __shared__ float lds[64][65];
  int t = threadIdx.x;
  int rr = t >> 4, cc = (t & 15) * 4;
#pragma unroll
  for (int pp = 0; pp < 4; ++pp) {
    float4 v = *(const float4*)&src[(size_t)(k0 + rr + pp * 16) * N + n0 + cc];
    lds[rr + pp * 16][cc + 0] = v.x;
    lds[rr + pp * 16][cc + 1] = v.y;
    lds[rr + pp * 16][cc + 2] = v.z;
    lds[rr + pp * 16][cc + 3] = v.w;
  }
  __syncthreads();
#pragma unroll
  for (int pp = 0; pp < 4; ++pp) {
    int nr = rr + pp * 16;
    ushort4 o;
    o.x = f2bf(lds[cc + 0][nr]);
    o.y = f2bf(lds[cc + 1][nr]);
    o.z = f2bf(lds[cc + 2][nr]);
    o.w = f2bf(lds[cc + 3][nr]);
    *(ushort4*)&dst[(size_t)(n0 + nr) * K + k0 + cc] = o;
  }
}

// ---------------------------------------------------------------------------
// fp32 -> bf16 elementwise
// ---------------------------------------------------------------------------
__global__ __launch_bounds__(256) void cvt_bf16(const float* __restrict__ in,
                                                unsigned short* __restrict__ out) {
  int i = (blockIdx.x * 256 + threadIdx.x) * 4;
  float4 v = *(const float4*)&in[i];
  ushort4 o;
  o.x = f2bf(v.x); o.y = f2bf(v.y); o.z = f2bf(v.z); o.w = f2bf(v.w);
  *(ushort4*)&out[i] = o;
}

// ---------------------------------------------------------------------------
// In-place row softmax over S=1024, bf16 scores, with attention mask.
// One block per (pair, q) row; 32 pairs.
// ---------------------------------------------------------------------------
__global__ __launch_bounds__(256) void softmax_k(unsigned short* __restrict__ Sc,
                                                 const int* __restrict__ mask) {
  int rowid = blockIdx.x;
  int pair = rowid >> 10;
  int q = rowid & 1023;
  int bb = pair >> 4;
  unsigned short* srow = Sc + ((size_t)pair << 20) + ((size_t)q << 10);
  const int* mrow = mask + (bb << 10);
  int t = threadIdx.x;
  ushort4 s4 = *(const ushort4*)&srow[t * 4];
  int4 m4 = *(const int4*)&mrow[t * 4];
  float v0 = m4.x ? bf2f(s4.x) : -1e30f;
  float v1 = m4.y ? bf2f(s4.y) : -1e30f;
  float v2 = m4.z ? bf2f(s4.z) : -1e30f;
  float v3 = m4.w ? bf2f(s4.w) : -1e30f;
  float mx = fmaxf(fmaxf(v0, v1), fmaxf(v2, v3));
  for (int o = 32; o > 0; o >>= 1) mx = fmaxf(mx, __shfl_xor(mx, o));
  __shared__ float red[4];
  __shared__ float red2[4];
  if ((t & 63) == 0) red[t >> 6] = mx;
  __syncthreads();
  mx = fmaxf(fmaxf(red[0], red[1]), fmaxf(red[2], red[3]));
  float e0 = (v0 > -1e29f) ? __expf(v0 - mx) : 0.f;
  float e1 = (v1 > -1e29f) ? __expf(v1 - mx) : 0.f;
  float e2 = (v2 > -1e29f) ? __expf(v2 - mx) : 0.f;
  float e3 = (v3 > -1e29f) ? __expf(v3 - mx) : 0.f;
  float sum = e0 + e1 + e2 + e3;
  for (int o = 32; o > 0; o >>= 1) sum += __shfl_xor(sum, o);
  if ((t & 63) == 0) red2[t >> 6] = sum;
  __syncthreads();
  sum = red2[0] + red2[1] + red2[2] + red2[3];
  float inv = 1.0f / sum;
  ushort4 o4;
  o4.x = f2bf(e0 * inv); o4.y = f2bf(e1 * inv);
  o4.z = f2bf(e2 * inv); o4.w = f2bf(e3 * inv);
  *(ushort4*)&srow[t * 4] = o4;
}

// ---------------------------------------------------------------------------
// LayerNorm over D=1024; writes fp32 + bf16 copies
// ---------------------------------------------------------------------------
__global__ __launch_bounds__(256) void ln_k(const float* __restrict__ in,
                                            const float* __restrict__ g,
                                            const float* __restrict__ b,
                                            float* __restrict__ outf,
                                            unsigned short* __restrict__ outb) {
  int row = blockIdx.x;
  int t = threadIdx.x;
  const float* x = in + ((size_t)row << 10);
  float4 v = *(const float4*)&x[t * 4];
  float s1 = v.x + v.y + v.z + v.w;
  float s2 = v.x * v.x + v.y * v.y + v.z * v.z + v.w * v.w;
  for (int o = 32; o > 0; o >>= 1) {
    s1 += __shfl_xor(s1, o);
    s2 += __shfl_xor(s2, o);
  }
  __shared__ float r1[4], r2[4];
  if ((t & 63) == 0) { r1[t >> 6] = s1; r2[t >> 6] = s2; }
  __syncthreads();
  s1 = r1[0] + r1[1] + r1[2] + r1[3];
  s2 = r2[0] + r2[1] + r2[2] + r2[3];
  float mean = s1 * (1.0f / 1024.0f);
  float var = s2 * (1.0f / 1024.0f) - mean * mean;
  float rstd = rsqrtf(var + 1e-12f);
  float4 gg = *(const float4*)&g[t * 4];
  float4 bb = *(const float4*)&b[t * 4];
  float o0 = (v.x - mean) * rstd * gg.x + bb.x;
  float o1 = (v.y - mean) * rstd * gg.y + bb.y;
  float o2 = (v.z - mean) * rstd * gg.z + bb.z;
  float o3 = (v.w - mean) * rstd * gg.w + bb.w;
  float4 of = make_float4(o0, o1, o2, o3);
  *(float4*)&outf[((size_t)row << 10) + t * 4] = of;
  ushort4 ob;
  ob.x = f2bf(o0); ob.y = f2bf(o1); ob.z = f2bf(o2); ob.w = f2bf(o3);
  *(ushort4*)&outb[((size_t)row << 10) + t * 4] = ob;
}

// ---------------------------------------------------------------------------
// Host driver
// ---------------------------------------------------------------------------
extern "C" void kernel_launch(void* const* d_in, const int* in_sizes, int n_in,
                              void* d_out, int out_size, void* d_ws, size_t ws_size,
                              hipStream_t stream) {
  (void)in_sizes; (void)n_in; (void)out_size; (void)ws_size;
  const float* x    = (const float*)d_in[0];
  const int*   mask = (const int*)d_in[1];
  const float* Wq   = (const float*)d_in[2];
  const float* bq   = (const float*)d_in[3];
  const float* Wk   = (const float*)d_in[4];
  const float* bk   = (const float*)d_in[5];
  const float* Wv   = (const float*)d_in[6];
  const float* bv   = (const float*)d_in[7];
  const float* Wo   = (const float*)d_in[8];
  const float* bo   = (const float*)d_in[9];
  const float* ln1g = (const float*)d_in[10];
  const float* ln1b = (const float*)d_in[11];
  const float* W1   = (const float*)d_in[12];
  const float* b1   = (const float*)d_in[13];
  const float* W2   = (const float*)d_in[14];
  const float* b2   = (const float*)d_in[15];
  const float* ln2g = (const float*)d_in[16];
  const float* ln2b = (const float*)d_in[17];
  float* out = (float*)d_out;

  char* wsp = (char*)d_ws;
  auto take = [&](size_t bytes) { char* r = wsp; wsp += bytes; return r; };
  unsigned short* wqkv = (unsigned short*)take(3072ull * 1024 * 2);
  unsigned short* wo_t = (unsigned short*)take(1024ull * 1024 * 2);
  unsigned short* w1_t = (unsigned short*)take(4096ull * 1024 * 2);
  unsigned short* w2_t = (unsigned short*)take(1024ull * 4096 * 2);
  float*          h    = (float*)take(2048ull * 1024 * 4);
  unsigned short* hbf  = (unsigned short*)take(2048ull * 1024 * 2);
  unsigned short* Qb   = (unsigned short*)take(2048ull * 1024 * 2);
  unsigned short* Kbuf = (unsigned short*)take(2048ull * 1024 * 2);
  unsigned short* VTb  = (unsigned short*)take(2048ull * 1024 * 2);
  unsigned short* ctxb = (unsigned short*)take(2048ull * 1024 * 2);
  float*          tmp  = (float*)take(2048ull * 1024 * 4);
  // scr: bf16 scores/probs for all 32 (b,h) pairs, softmaxed in place.
  // ffb (FFN hidden, bf16 2048x4096 = 16MB) aliases scr (64MB): disjoint in time.
  unsigned short* scr  = (unsigned short*)take(32ull * 1024 * 1024 * 2);
  unsigned short* ffb  = scr;

  cvt_bf16<<<2048, 256, 0, stream>>>(x, hbf);

  for (int l = 0; l < 4; ++l) {
    transpose_w<<<3072, 256, 0, stream>>>(
        Wq + (size_t)l * 1048576, Wk + (size_t)l * 1048576,
        Wv + (size_t)l * 1048576, Wo + (size_t)l * 1048576,
        W1 + (size_t)l * 4194304, W2 + (size_t)l * 4194304,
        wqkv, wo_t, w1_t, w2_t);

    // QKV projection: [2048 x 3072] = hbf [2048x1024] * wqkv^T
    {
      EpParams p{};
      p.bias = bq + l * 1024; p.bias2 = bk + l * 1024; p.bias3 = bv + l * 1024;
      p.outb = Qb; p.outb2 = Kbuf; p.outb3 = VTb;
      gemm_bt<128, 128, 2, 2, 4, 4, 0><<<dim3(24, 16, 1), 256, 0, stream>>>(
          hbf, wqkv, 1024, 16, 0, 0, p);
    }

    // Scores for all 32 (b,h) pairs: S[pair][q][k] bf16
    {
      EpParams p{};
      p.outb = scr; p.strideCz = 1 << 20;
      gemm_bt<128, 128, 2, 2, 4, 4, 1><<<dim3(8, 8, 32), 256, 0, stream>>>(
          Qb, Kbuf, 64, 1, 65536, 65536, p);
    }
    softmax_k<<<32768, 256, 0, stream>>>(scr, mask);
    // ctx = P @ V^T, all 32 pairs
    {
      EpParams p{};
      p.outb = ctxb; p.pair_base = 0;
      gemm_bt<128, 64, 2, 2, 4, 2, 2><<<dim3(1, 8, 32), 256, 0, stream>>>(
          scr, VTb, 1024, 16, 1 << 20, 65536, p);
    }

    // O projection + bias + residual
    {
      EpParams p{};
      p.bias = bo + l * 1024; p.res = (l == 0 ? x : h); p.outf = tmp; p.ldC = 1024;
      gemm_bt<128, 64, 2, 2, 4, 2, 3><<<dim3(16, 16, 1), 256, 0, stream>>>(
          ctxb, wo_t, 1024, 16, 0, 0, p);
    }
    ln_k<<<2048, 256, 0, stream>>>(tmp, ln1g + l * 1024, ln1b + l * 1024, h, hbf);

    // FFN1 + GELU
    {
      EpParams p{};
      p.bias = b1 + l * 4096; p.outb = ffb; p.ldC = 4096;
      gemm_bt<128, 128, 2, 2, 4, 4, 4><<<dim3(32, 16, 1), 256, 0, stream>>>(
          hbf, w1_t, 1024, 16, 0, 0, p);
    }
    // FFN2 + bias + residual
    {
      EpParams p{};
      p.bias = b2 + l * 1024; p.res = h; p.outf = tmp; p.ldC = 1024;
      gemm_bt<128, 64, 2, 2, 4, 2, 3><<<dim3(16, 16, 1), 256, 0, stream>>>(
          ffb, w2_t, 4096, 64, 0, 0, p);
    }
    ln_k<<<2048, 256, 0, stream>>>(tmp, ln2g + l * 1024, ln2b + l * 1024,
                                   (l == 3 ? out : h), hbf);
  }
}

// Round 3
// 1014.584 us; speedup vs baseline: 1.6769x; 1.1308x over previous
//
#include <hip/hip_runtime.h>
#include <cstdint>
#include <cstddef>

// ---------------------------------------------------------------------------
// Types
// ---------------------------------------------------------------------------
using bf16x8 = __attribute__((ext_vector_type(8))) short;
using f32x4  = __attribute__((ext_vector_type(4))) float;

__device__ __forceinline__ unsigned short f2bf(float f) {
  unsigned int u = __builtin_bit_cast(unsigned int, f);
  u += 0x7fffu + ((u >> 16) & 1u);
  return (unsigned short)(u >> 16);
}
__device__ __forceinline__ float bf2f(unsigned short h) {
  unsigned int u = ((unsigned int)h) << 16;
  return __builtin_bit_cast(float, u);
}

// async global->LDS 16B per lane. LDS dest must be wave-uniform-base + lane*16.
__device__ __forceinline__ void async_cp16(const void* g, void* l) {
  __builtin_amdgcn_global_load_lds(
      (__attribute__((address_space(1))) void*)(g),
      (__attribute__((address_space(3))) void*)(l), 16, 0, 0);
}

// ---------------------------------------------------------------------------
// Epilogue params
// ---------------------------------------------------------------------------
struct EpParams {
  const float* bias;    // col bias
  const float* bias2;   // (qkv) k bias
  const float* bias3;   // (qkv) v bias
  const float* res;     // residual fp32 [M][ldC]
  float* outf;          // fp32 out
  unsigned short* outb; // bf16 out
  unsigned short* outb2;
  unsigned short* outb3;
  long long strideCz;   // elements
  int ldC;
  int pair_base;
};

// EP: 0=QKV scatter, 1=scores bf16, 2=ctx scatter, 3=bias+residual f32 (split-K
// aware: z0 adds bias+res, z>0 writes raw partial to outf+z*strideCz), 4=gelu bf16
// LDS XOR swizzle: LDS slot (row, chunk) holds global 16B-chunk (chunk ^ (row&7)).
template <int BM, int BN, int WGM, int WGN, int FI, int FJ, int EP>
__global__ __launch_bounds__(256, 2) void gemm_bt(
    const unsigned short* __restrict__ A, const unsigned short* __restrict__ B,
    int K, int kTiles, long long strideAz, long long strideBz, EpParams p) {
  __shared__ alignas(16) unsigned short As[BM * 64];
  __shared__ alignas(16) unsigned short Bs[BN * 64];
  const int t = threadIdx.x;
  const int lane = t & 63;
  const int w = t >> 6;
  const int wr = w / WGN, wc = w % WGN;
  const int lm = lane & 15, quad = lane >> 4;
  const int m0 = blockIdx.y * BM, n0 = blockIdx.x * BN;
  const int bz = blockIdx.z;
  A += (long long)bz * strideAz;
  B += (long long)bz * strideBz;

  f32x4 acc[FI][FJ] = {};

  const int rowA = t >> 3;                       // 0..31 within a staging step
  const int colSw = ((t & 7) ^ (rowA & 7)) * 8;  // swizzled source column

  for (int kt = 0; kt < kTiles; ++kt) {
    const unsigned short* ga = A + (size_t)(m0 + rowA) * K + kt * 64 + colSw;
    const unsigned short* gb = B + (size_t)(n0 + rowA) * K + kt * 64 + colSw;
#pragma unroll
    for (int s = 0; s < BM / 32; ++s)
      async_cp16(ga + (size_t)s * 32 * K, &As[s * 2048 + t * 8]);
#pragma unroll
    for (int s = 0; s < BN / 32; ++s)
      async_cp16(gb + (size_t)s * 32 * K, &Bs[s * 2048 + t * 8]);
    __syncthreads();
#pragma unroll
    for (int ks = 0; ks < 2; ++ks) {
      bf16x8 af[FI], bfr[FJ];
#pragma unroll
      for (int i = 0; i < FI; ++i) {
        int ra = wr * FI * 16 + i * 16 + lm;
        af[i] = *(const bf16x8*)&As[ra * 64 + (((ks * 4 + quad) ^ (ra & 7)) << 3)];
      }
#pragma unroll
      for (int j = 0; j < FJ; ++j) {
        int rb = wc * FJ * 16 + j * 16 + lm;
        bfr[j] = *(const bf16x8*)&Bs[rb * 64 + (((ks * 4 + quad) ^ (rb & 7)) << 3)];
      }
#pragma unroll
      for (int i = 0; i < FI; ++i)
#pragma unroll
        for (int j = 0; j < FJ; ++j)
          acc[i][j] = __builtin_amdgcn_mfma_f32_16x16x32_bf16(af[i], bfr[j], acc[i][j], 0, 0, 0);
    }
    __syncthreads();
  }

#pragma unroll
  for (int i = 0; i < FI; ++i) {
#pragma unroll
    for (int j = 0; j < FJ; ++j) {
#pragma unroll
      for (int r = 0; r < 4; ++r) {
        int row = m0 + wr * FI * 16 + i * 16 + quad * 4 + r;
        int col = n0 + wc * FJ * 16 + j * 16 + lm;
        float v = acc[i][j][r];
        if constexpr (EP == 1) {
          p.outb[(long long)bz * p.strideCz + ((size_t)row << 10) + col] = f2bf(v);
        } else if constexpr (EP == 0) {
          int bb = row >> 10, s = row & 1023;
          if (col < 1024) {
            float q = (v + p.bias[col]) * 0.125f;
            int hd = col >> 6, dh = col & 63;
            p.outb[((size_t)(bb * 16 + hd) << 16) + (s << 6) + dh] = f2bf(q);
          } else if (col < 2048) {
            int c2 = col - 1024;
            float kk = v + p.bias2[c2];
            int hd = c2 >> 6, dh = c2 & 63;
            p.outb2[((size_t)(bb * 16 + hd) << 16) + (s << 6) + dh] = f2bf(kk);
          } else {
            int c3 = col - 2048;
            float vv = v + p.bias3[c3];
            int hd = c3 >> 6, dh = c3 & 63;
            p.outb3[((size_t)(bb * 16 + hd) << 16) + ((size_t)dh << 10) + s] = f2bf(vv);
          }
        } else if constexpr (EP == 2) {
          int pair = p.pair_base + bz;
          int bb = pair >> 4, hd = pair & 15;
          p.outb[((size_t)bb << 20) + ((size_t)row << 10) + (hd << 6) + col] = f2bf(v);
        } else if constexpr (EP == 3) {
          size_t idx = (size_t)row * p.ldC + col;
          float add = (bz == 0) ? (p.bias[col] + p.res[idx]) : 0.0f;
          p.outf[(long long)bz * p.strideCz + idx] = v + add;
        } else if constexpr (EP == 4) {
          float val = v + p.bias[col];
          float g = 0.5f * val * (1.0f + erff(val * 0.70710678118654752f));
          p.outb[(size_t)row * p.ldC + col] = f2bf(g);
        }
      }
    }
  }
}

// ---------------------------------------------------------------------------
// Weight convert + transpose: fp32 [K][N] -> bf16 [N][K]  (BT layout)
// ---------------------------------------------------------------------------
__global__ __launch_bounds__(256) void transpose_w(
    const float* __restrict__ Wq, const float* __restrict__ Wk,
    const float* __restrict__ Wv, const float* __restrict__ Wo,
    const float* __restrict__ W1, const float* __restrict__ W2,
    unsigned short* __restrict__ wqkv, unsigned short* __restrict__ wo,
    unsigned short* __restrict__ w1, unsigned short* __restrict__ w2) {
  int blk = blockIdx.x;
  int kind, local;
  if (blk < 1024) { kind = blk >> 8; local = blk & 255; }
  else if (blk < 2048) { kind = 4; local = blk - 1024; }
  else { kind = 5; local = blk - 2048; }
  const float* src;
  unsigned short* dst;
  int K, N;
  switch (kind) {
    case 0: src = Wq; dst = wqkv;                  K = 1024; N = 1024; break;
    case 1: src = Wk; dst = wqkv + 1024 * 1024;    K = 1024; N = 1024; break;
    case 2: src = Wv; dst = wqkv + 2048 * 1024;    K = 1024; N = 1024; break;
    case 3: src = Wo; dst = wo;                    K = 1024; N = 1024; break;
    case 4: src = W1; dst = w1;                    K = 1024; N = 4096; break;
    default: src = W2; dst = w2;                   K = 4096; N = 1024; break;
  }
  int tilesK = K >> 6;
  int tk = local % tilesK, tn = local / tilesK;
  int k0 = tk << 6, n0 = tn << 6;
  __shared__ float lds[64][65];
  int t = threadIdx.x;
  int rr = t >> 4, cc = (t & 15) * 4;
#pragma unroll
  for (int pp = 0; pp < 4; ++pp) {
    float4 v = *(const float4*)&src[(size_t)(k0 + rr + pp * 16) * N + n0 + cc];
    lds[rr + pp * 16][cc + 0] = v.x;
    lds[rr + pp * 16][cc + 1] = v.y;
    lds[rr + pp * 16][cc + 2] = v.z;
    lds[rr + pp * 16][cc + 3] = v.w;
  }
  __syncthreads();
#pragma unroll
  for (int pp = 0; pp < 4; ++pp) {
    int nr = rr + pp * 16;
    ushort4 o;
    o.x = f2bf(lds[cc + 0][nr]);
    o.y = f2bf(lds[cc + 1][nr]);
    o.z = f2bf(lds[cc + 2][nr]);
    o.w = f2bf(lds[cc + 3][nr]);
    *(ushort4*)&dst[(size_t)(n0 + nr) * K + k0 + cc] = o;
  }
}

// ---------------------------------------------------------------------------
// fp32 -> bf16 elementwise
// ---------------------------------------------------------------------------
__global__ __launch_bounds__(256) void cvt_bf16(const float* __restrict__ in,
                                                unsigned short* __restrict__ out) {
  int i = (blockIdx.x * 256 + threadIdx.x) * 4;
  float4 v = *(const float4*)&in[i];
  ushort4 o;
  o.x = f2bf(v.x); o.y = f2bf(v.y); o.z = f2bf(v.z); o.w = f2bf(v.w);
  *(ushort4*)&out[i] = o;
}

// ---------------------------------------------------------------------------
// In-place row softmax over S=1024, bf16 scores, with attention mask.
// ---------------------------------------------------------------------------
__global__ __launch_bounds__(256) void softmax_k(unsigned short* __restrict__ Sc,
                                                 const int* __restrict__ mask) {
  int rowid = blockIdx.x;
  int pair = rowid >> 10;
  int q = rowid & 1023;
  int bb = pair >> 4;
  unsigned short* srow = Sc + ((size_t)pair << 20) + ((size_t)q << 10);
  const int* mrow = mask + (bb << 10);
  int t = threadIdx.x;
  ushort4 s4 = *(const ushort4*)&srow[t * 4];
  int4 m4 = *(const int4*)&mrow[t * 4];
  float v0 = m4.x ? bf2f(s4.x) : -1e30f;
  float v1 = m4.y ? bf2f(s4.y) : -1e30f;
  float v2 = m4.z ? bf2f(s4.z) : -1e30f;
  float v3 = m4.w ? bf2f(s4.w) : -1e30f;
  float mx = fmaxf(fmaxf(v0, v1), fmaxf(v2, v3));
  for (int o = 32; o > 0; o >>= 1) mx = fmaxf(mx, __shfl_xor(mx, o));
  __shared__ float red[4];
  __shared__ float red2[4];
  if ((t & 63) == 0) red[t >> 6] = mx;
  __syncthreads();
  mx = fmaxf(fmaxf(red[0], red[1]), fmaxf(red[2], red[3]));
  float e0 = (v0 > -1e29f) ? __expf(v0 - mx) : 0.f;
  float e1 = (v1 > -1e29f) ? __expf(v1 - mx) : 0.f;
  float e2 = (v2 > -1e29f) ? __expf(v2 - mx) : 0.f;
  float e3 = (v3 > -1e29f) ? __expf(v3 - mx) : 0.f;
  float sum = e0 + e1 + e2 + e3;
  for (int o = 32; o > 0; o >>= 1) sum += __shfl_xor(sum, o);
  if ((t & 63) == 0) red2[t >> 6] = sum;
  __syncthreads();
  sum = red2[0] + red2[1] + red2[2] + red2[3];
  float inv = 1.0f / sum;
  ushort4 o4;
  o4.x = f2bf(e0 * inv); o4.y = f2bf(e1 * inv);
  o4.z = f2bf(e2 * inv); o4.w = f2bf(e3 * inv);
  *(ushort4*)&srow[t * 4] = o4;
}

// ---------------------------------------------------------------------------
// LayerNorm over D=1024; in = partial0, in2 = partial1 (summed); writes
// fp32 + bf16 copies.
// ---------------------------------------------------------------------------
__global__ __launch_bounds__(256) void ln_k(const float* __restrict__ in,
                                            const float* __restrict__ in2,
                                            const float* __restrict__ g,
                                            const float* __restrict__ b,
                                            float* __restrict__ outf,
                                            unsigned short* __restrict__ outb) {
  int row = blockIdx.x;
  int t = threadIdx.x;
  const float* x = in + ((size_t)row << 10);
  const float* x2 = in2 + ((size_t)row << 10);
  float4 v = *(const float4*)&x[t * 4];
  float4 v2 = *(const float4*)&x2[t * 4];
  v.x += v2.x; v.y += v2.y; v.z += v2.z; v.w += v2.w;
  float s1 = v.x + v.y + v.z + v.w;
  float s2 = v.x * v.x + v.y * v.y + v.z * v.z + v.w * v.w;
  for (int o = 32; o > 0; o >>= 1) {
    s1 += __shfl_xor(s1, o);
    s2 += __shfl_xor(s2, o);
  }
  __shared__ float r1[4], r2[4];
  if ((t & 63) == 0) { r1[t >> 6] = s1; r2[t >> 6] = s2; }
  __syncthreads();
  s1 = r1[0] + r1[1] + r1[2] + r1[3];
  s2 = r2[0] + r2[1] + r2[2] + r2[3];
  float mean = s1 * (1.0f / 1024.0f);
  float var = s2 * (1.0f / 1024.0f) - mean * mean;
  float rstd = rsqrtf(var + 1e-12f);
  float4 gg = *(const float4*)&g[t * 4];
  float4 bb = *(const float4*)&b[t * 4];
  float o0 = (v.x - mean) * rstd * gg.x + bb.x;
  float o1 = (v.y - mean) * rstd * gg.y + bb.y;
  float o2 = (v.z - mean) * rstd * gg.z + bb.z;
  float o3 = (v.w - mean) * rstd * gg.w + bb.w;
  float4 of = make_float4(o0, o1, o2, o3);
  *(float4*)&outf[((size_t)row << 10) + t * 4] = of;
  ushort4 ob;
  ob.x = f2bf(o0); ob.y = f2bf(o1); ob.z = f2bf(o2); ob.w = f2bf(o3);
  *(ushort4*)&outb[((size_t)row << 10) + t * 4] = ob;
}

// ---------------------------------------------------------------------------
// Host driver
// ---------------------------------------------------------------------------
extern "C" void kernel_launch(void* const* d_in, const int* in_sizes, int n_in,
                              void* d_out, int out_size, void* d_ws, size_t ws_size,
                              hipStream_t stream) {
  (void)in_sizes; (void)n_in; (void)out_size; (void)ws_size;
  const float* x    = (const float*)d_in[0];
  const int*   mask = (const int*)d_in[1];
  const float* Wq   = (const float*)d_in[2];
  const float* bq   = (const float*)d_in[3];
  const float* Wk   = (const float*)d_in[4];
  const float* bk   = (const float*)d_in[5];
  const float* Wv   = (const float*)d_in[6];
  const float* bv   = (const float*)d_in[7];
  const float* Wo   = (const float*)d_in[8];
  const float* bo   = (const float*)d_in[9];
  const float* ln1g = (const float*)d_in[10];
  const float* ln1b = (const float*)d_in[11];
  const float* W1   = (const float*)d_in[12];
  const float* b1   = (const float*)d_in[13];
  const float* W2   = (const float*)d_in[14];
  const float* b2   = (const float*)d_in[15];
  const float* ln2g = (const float*)d_in[16];
  const float* ln2b = (const float*)d_in[17];
  float* out = (float*)d_out;

  char* wsp = (char*)d_ws;
  auto take = [&](size_t bytes) { char* r = wsp; wsp += bytes; return r; };
  unsigned short* wqkv = (unsigned short*)take(3072ull * 1024 * 2);
  unsigned short* wo_t = (unsigned short*)take(1024ull * 1024 * 2);
  unsigned short* w1_t = (unsigned short*)take(4096ull * 1024 * 2);
  unsigned short* w2_t = (unsigned short*)take(1024ull * 4096 * 2);
  float*          h    = (float*)take(2048ull * 1024 * 4);
  unsigned short* hbf  = (unsigned short*)take(2048ull * 1024 * 2);
  unsigned short* Qb   = (unsigned short*)take(2048ull * 1024 * 2);
  unsigned short* Kbuf = (unsigned short*)take(2048ull * 1024 * 2);
  unsigned short* VTb  = (unsigned short*)take(2048ull * 1024 * 2);
  unsigned short* ctxb = (unsigned short*)take(2048ull * 1024 * 2);
  float*          tmp  = (float*)take(2ull * 2048 * 1024 * 4);  // split-K partials
  unsigned short* scr  = (unsigned short*)take(32ull * 1024 * 1024 * 2);
  unsigned short* ffb  = scr;  // aliases scr; disjoint in time
  const long long TMPZ = 2048ll * 1024;

  cvt_bf16<<<2048, 256, 0, stream>>>(x, hbf);

  for (int l = 0; l < 4; ++l) {
    transpose_w<<<3072, 256, 0, stream>>>(
        Wq + (size_t)l * 1048576, Wk + (size_t)l * 1048576,
        Wv + (size_t)l * 1048576, Wo + (size_t)l * 1048576,
        W1 + (size_t)l * 4194304, W2 + (size_t)l * 4194304,
        wqkv, wo_t, w1_t, w2_t);

    // QKV projection: [2048 x 3072], 64x128 tile -> 768 blocks (3/CU)
    {
      EpParams p{};
      p.bias = bq + l * 1024; p.bias2 = bk + l * 1024; p.bias3 = bv + l * 1024;
      p.outb = Qb; p.outb2 = Kbuf; p.outb3 = VTb;
      gemm_bt<64, 128, 2, 2, 2, 4, 0><<<dim3(24, 32, 1), 256, 0, stream>>>(
          hbf, wqkv, 1024, 16, 0, 0, p);
    }

    // Scores: S[pair][q][k] bf16, all 32 pairs
    {
      EpParams p{};
      p.outb = scr; p.strideCz = 1 << 20;
      gemm_bt<128, 128, 2, 2, 4, 4, 1><<<dim3(8, 8, 32), 256, 0, stream>>>(
          Qb, Kbuf, 64, 1, 65536, 65536, p);
    }
    softmax_k<<<32768, 256, 0, stream>>>(scr, mask);
    // ctx = P @ V^T: 64x64 tile -> 512 blocks (2/CU)
    {
      EpParams p{};
      p.outb = ctxb; p.pair_base = 0;
      gemm_bt<64, 64, 2, 2, 2, 2, 2><<<dim3(1, 16, 32), 256, 0, stream>>>(
          scr, VTb, 1024, 16, 1 << 20, 65536, p);
    }

    // O projection + bias + residual, split-K=2 -> 512 blocks
    {
      EpParams p{};
      p.bias = bo + l * 1024; p.res = (l == 0 ? x : h);
      p.outf = tmp; p.strideCz = TMPZ; p.ldC = 1024;
      gemm_bt<128, 64, 2, 2, 4, 2, 3><<<dim3(16, 16, 2), 256, 0, stream>>>(
          ctxb, wo_t, 1024, 8, 512, 512, p);
    }
    ln_k<<<2048, 256, 0, stream>>>(tmp, tmp + TMPZ,
                                   ln1g + l * 1024, ln1b + l * 1024, h, hbf);

    // FFN1 + GELU: 64x128 tile -> 1024 blocks (4/CU)
    {
      EpParams p{};
      p.bias = b1 + l * 4096; p.outb = ffb; p.ldC = 4096;
      gemm_bt<64, 128, 2, 2, 2, 4, 4><<<dim3(32, 32, 1), 256, 0, stream>>>(
          hbf, w1_t, 1024, 16, 0, 0, p);
    }
    // FFN2 + bias + residual, split-K=2 -> 512 blocks
    {
      EpParams p{};
      p.bias = b2 + l * 1024; p.res = h;
      p.outf = tmp; p.strideCz = TMPZ; p.ldC = 1024;
      gemm_bt<128, 64, 2, 2, 4, 2, 3><<<dim3(16, 16, 2), 256, 0, stream>>>(
          ffb, w2_t, 4096, 32, 2048, 2048, p);
    }
    ln_k<<<2048, 256, 0, stream>>>(tmp, tmp + TMPZ,
                                   ln2g + l * 1024, ln2b + l * 1024,
                                   (l == 3 ? out : h), hbf);
  }
}

// Round 4
// 824.361 us; speedup vs baseline: 2.0639x; 1.2308x over previous
//
#include <hip/hip_runtime.h>
#include <cstdint>
#include <cstddef>

// ---------------------------------------------------------------------------
// Types
// ---------------------------------------------------------------------------
using bf16x8 = __attribute__((ext_vector_type(8))) short;
using f32x4  = __attribute__((ext_vector_type(4))) float;

__device__ __forceinline__ unsigned short f2bf(float f) {
  unsigned int u = __builtin_bit_cast(unsigned int, f);
  u += 0x7fffu + ((u >> 16) & 1u);
  return (unsigned short)(u >> 16);
}
__device__ __forceinline__ float bf2f(unsigned short h) {
  unsigned int u = ((unsigned int)h) << 16;
  return __builtin_bit_cast(float, u);
}

// async global->LDS 16B per lane. LDS dest must be wave-uniform-base + lane*16.
__device__ __forceinline__ void async_cp16(const void* g, void* l) {
  __builtin_amdgcn_global_load_lds(
      (__attribute__((address_space(1))) void*)(g),
      (__attribute__((address_space(3))) void*)(l), 16, 0, 0);
}

// ---------------------------------------------------------------------------
// Epilogue params
// ---------------------------------------------------------------------------
struct EpParams {
  const float* bias;    // col bias
  const float* bias2;   // (qkv) k bias
  const float* bias3;   // (qkv) v bias
  const float* res;     // residual fp32 [M][ldC]
  float* outf;          // fp32 out
  unsigned short* outb; // bf16 out
  unsigned short* outb2;
  unsigned short* outb3;
  long long strideCz;   // elements
  int ldC;
  int pair_base;
};

// EP: 0=QKV scatter, 3=bias+residual f32 (split-K aware), 4=gelu bf16
// LDS XOR swizzle: LDS slot (row, chunk) holds global 16B-chunk (chunk ^ (row&7)).
template <int BM, int BN, int WGM, int WGN, int FI, int FJ, int EP>
__global__ __launch_bounds__(256, 2) void gemm_bt(
    const unsigned short* __restrict__ A, const unsigned short* __restrict__ B,
    int K, int kTiles, long long strideAz, long long strideBz, EpParams p) {
  __shared__ alignas(16) unsigned short As[BM * 64];
  __shared__ alignas(16) unsigned short Bs[BN * 64];
  const int t = threadIdx.x;
  const int lane = t & 63;
  const int w = t >> 6;
  const int wr = w / WGN, wc = w % WGN;
  const int lm = lane & 15, quad = lane >> 4;
  const int m0 = blockIdx.y * BM, n0 = blockIdx.x * BN;
  const int bz = blockIdx.z;
  A += (long long)bz * strideAz;
  B += (long long)bz * strideBz;

  f32x4 acc[FI][FJ] = {};

  const int rowA = t >> 3;                       // 0..31 within a staging step
  const int colSw = ((t & 7) ^ (rowA & 7)) * 8;  // swizzled source column

  for (int kt = 0; kt < kTiles; ++kt) {
    const unsigned short* ga = A + (size_t)(m0 + rowA) * K + kt * 64 + colSw;
    const unsigned short* gb = B + (size_t)(n0 + rowA) * K + kt * 64 + colSw;
#pragma unroll
    for (int s = 0; s < BM / 32; ++s)
      async_cp16(ga + (size_t)s * 32 * K, &As[s * 2048 + t * 8]);
#pragma unroll
    for (int s = 0; s < BN / 32; ++s)
      async_cp16(gb + (size_t)s * 32 * K, &Bs[s * 2048 + t * 8]);
    __syncthreads();
#pragma unroll
    for (int ks = 0; ks < 2; ++ks) {
      bf16x8 af[FI], bfr[FJ];
#pragma unroll
      for (int i = 0; i < FI; ++i) {
        int ra = wr * FI * 16 + i * 16 + lm;
        af[i] = *(const bf16x8*)&As[ra * 64 + (((ks * 4 + quad) ^ (ra & 7)) << 3)];
      }
#pragma unroll
      for (int j = 0; j < FJ; ++j) {
        int rb = wc * FJ * 16 + j * 16 + lm;
        bfr[j] = *(const bf16x8*)&Bs[rb * 64 + (((ks * 4 + quad) ^ (rb & 7)) << 3)];
      }
#pragma unroll
      for (int i = 0; i < FI; ++i)
#pragma unroll
        for (int j = 0; j < FJ; ++j)
          acc[i][j] = __builtin_amdgcn_mfma_f32_16x16x32_bf16(af[i], bfr[j], acc[i][j], 0, 0, 0);
    }
    __syncthreads();
  }

#pragma unroll
  for (int i = 0; i < FI; ++i) {
#pragma unroll
    for (int j = 0; j < FJ; ++j) {
#pragma unroll
      for (int r = 0; r < 4; ++r) {
        int row = m0 + wr * FI * 16 + i * 16 + quad * 4 + r;
        int col = n0 + wc * FJ * 16 + j * 16 + lm;
        float v = acc[i][j][r];
        if constexpr (EP == 0) {
          int bb = row >> 10, s = row & 1023;
          if (col < 1024) {
            float q = (v + p.bias[col]) * 0.125f;
            int hd = col >> 6, dh = col & 63;
            p.outb[((size_t)(bb * 16 + hd) << 16) + (s << 6) + dh] = f2bf(q);
          } else if (col < 2048) {
            int c2 = col - 1024;
            float kk = v + p.bias2[c2];
            int hd = c2 >> 6, dh = c2 & 63;
            p.outb2[((size_t)(bb * 16 + hd) << 16) + (s << 6) + dh] = f2bf(kk);
          } else {
            int c3 = col - 2048;
            float vv = v + p.bias3[c3];
            int hd = c3 >> 6, dh = c3 & 63;
            p.outb3[((size_t)(bb * 16 + hd) << 16) + ((size_t)dh << 10) + s] = f2bf(vv);
          }
        } else if constexpr (EP == 3) {
          size_t idx = (size_t)row * p.ldC + col;
          float add = (bz == 0) ? (p.bias[col] + p.res[idx]) : 0.0f;
          p.outf[(long long)bz * p.strideCz + idx] = v + add;
        } else if constexpr (EP == 4) {
          float val = v + p.bias[col];
          float g = 0.5f * val * (1.0f + erff(val * 0.70710678118654752f));
          p.outb[(size_t)row * p.ldC + col] = f2bf(g);
        }
      }
    }
  }
}

// ---------------------------------------------------------------------------
// Fused flash attention (prefill). One block = (64-row Q-tile, pair).
// Wave grid 4x1: wave w owns q-rows w*16..w*16+15 entirely -> softmax
// reductions are 16-lane shuffles; P round-trips LDS per-wave (no barrier).
// Q pre-scaled by 1/8 at QKV epilogue. K-tile = 128 keys.
// ---------------------------------------------------------------------------
__global__ __launch_bounds__(256, 2) void flash_attn(
    const unsigned short* __restrict__ Qb, const unsigned short* __restrict__ Kb,
    const unsigned short* __restrict__ VTb, const int* __restrict__ mask,
    unsigned short* __restrict__ ctx) {
  __shared__ alignas(16) unsigned short Qs[64 * 64];
  __shared__ alignas(16) unsigned short Ks[128 * 64];
  __shared__ alignas(16) unsigned short VTs[64 * 128];
  __shared__ alignas(16) unsigned short Ps[64 * 128];
  const int t = threadIdx.x;
  const int lane = t & 63;
  const int w = t >> 6;
  const int lm = lane & 15, quad = lane >> 4;
  const int pair = blockIdx.y;
  const int q0 = blockIdx.x * 64;
  const int bb = pair >> 4, hd = pair & 15;
  const unsigned short* Qp = Qb + ((size_t)pair << 16);
  const unsigned short* Kp = Kb + ((size_t)pair << 16);
  const unsigned short* Vp = VTb + ((size_t)pair << 16);
  const int* mrow = mask + (bb << 10);

  // stage Q (64 rows x 64), XOR-swizzled chunks
  {
    const int rowA = t >> 3;
    const int c = t & 7;
#pragma unroll
    for (int s = 0; s < 2; ++s) {
      int row = s * 32 + rowA;
      async_cp16(Qp + (size_t)(q0 + row) * 64 + ((c ^ (row & 7)) << 3),
                 &Qs[s * 2048 + t * 8]);
    }
  }

  f32x4 o_acc[4] = {};
  float m_run[4], l_run[4];
#pragma unroll
  for (int r = 0; r < 4; ++r) { m_run[r] = -3e38f; l_run[r] = 0.f; }

  for (int k0 = 0; k0 < 1024; k0 += 128) {
    __syncthreads();  // previous iteration done reading Ks/VTs (and Q ready)
    {
      const int rowA = t >> 3;
      const int c = t & 7;
#pragma unroll
      for (int s = 0; s < 4; ++s) {
        int row = s * 32 + rowA;
        async_cp16(Kp + (size_t)(k0 + row) * 64 + ((c ^ (row & 7)) << 3),
                   &Ks[s * 2048 + t * 8]);
      }
      const int rowV = t >> 4;
      const int cv = t & 15;
#pragma unroll
      for (int s = 0; s < 4; ++s) {
        int row = s * 16 + rowV;
        async_cp16(Vp + (size_t)row * 1024 + k0 + ((cv ^ (row & 15)) << 3),
                   &VTs[s * 2048 + t * 8]);
      }
    }
    int mv[8];
#pragma unroll
    for (int j = 0; j < 8; ++j) mv[j] = mrow[k0 + j * 16 + lm];
    __syncthreads();  // staged tiles visible

    // ---- QK^T: wave w -> 16 q-rows x 128 keys ----
    f32x4 s_acc[8] = {};
    {
      const int ra = w * 16 + lm;
      bf16x8 aq[2];
#pragma unroll
      for (int ks = 0; ks < 2; ++ks)
        aq[ks] = *(const bf16x8*)&Qs[ra * 64 + (((ks * 4 + quad) ^ (ra & 7)) << 3)];
#pragma unroll
      for (int j = 0; j < 8; ++j) {
        const int rb = j * 16 + lm;
#pragma unroll
        for (int ks = 0; ks < 2; ++ks) {
          bf16x8 bk_ = *(const bf16x8*)&Ks[rb * 64 + (((ks * 4 + quad) ^ (rb & 7)) << 3)];
          s_acc[j] = __builtin_amdgcn_mfma_f32_16x16x32_bf16(aq[ks], bk_, s_acc[j], 0, 0, 0);
        }
      }
    }

    // ---- mask + online softmax (rows = quad*4+r, cols = lm+16j) ----
    float mt[4];
#pragma unroll
    for (int r = 0; r < 4; ++r) mt[r] = -3e38f;
#pragma unroll
    for (int j = 0; j < 8; ++j)
#pragma unroll
      for (int r = 0; r < 4; ++r) {
        float sv = mv[j] ? s_acc[j][r] : -1e30f;
        s_acc[j][r] = sv;
        mt[r] = fmaxf(mt[r], sv);
      }
#pragma unroll
    for (int r = 0; r < 4; ++r)
#pragma unroll
      for (int off = 1; off < 16; off <<= 1)
        mt[r] = fmaxf(mt[r], __shfl_xor(mt[r], off));
    float alpha[4], lt[4];
#pragma unroll
    for (int r = 0; r < 4; ++r) {
      float mn = fmaxf(m_run[r], mt[r]);
      alpha[r] = __expf(m_run[r] - mn);
      m_run[r] = mn;
      lt[r] = 0.f;
    }
#pragma unroll
    for (int j = 0; j < 8; ++j)
#pragma unroll
      for (int r = 0; r < 4; ++r) {
        float pv = __expf(s_acc[j][r] - m_run[r]);
        s_acc[j][r] = pv;
        lt[r] += pv;
      }
#pragma unroll
    for (int r = 0; r < 4; ++r) {
#pragma unroll
      for (int off = 1; off < 16; off <<= 1) lt[r] += __shfl_xor(lt[r], off);
      l_run[r] = l_run[r] * alpha[r] + lt[r];
    }
#pragma unroll
    for (int jf = 0; jf < 4; ++jf)
#pragma unroll
      for (int r = 0; r < 4; ++r) o_acc[jf][r] *= alpha[r];

    // ---- P: C-layout regs -> LDS A-layout (per-wave rows, swizzled) ----
#pragma unroll
    for (int j = 0; j < 8; ++j) {
      const int chunk = 2 * j + (lm >> 3);
#pragma unroll
      for (int r = 0; r < 4; ++r) {
        const int row = w * 16 + quad * 4 + r;
        Ps[row * 128 + ((chunk ^ (row & 15)) << 3) + (lm & 7)] = f2bf(s_acc[j][r]);
      }
    }

    // ---- PV: wave w -> 16 rows x 64 dh, K=128 ----
    const int ra = w * 16 + lm;
#pragma unroll
    for (int kk = 0; kk < 4; ++kk) {
      bf16x8 ap = *(const bf16x8*)&Ps[ra * 128 + (((kk * 4 + quad) ^ (ra & 15)) << 3)];
#pragma unroll
      for (int jf = 0; jf < 4; ++jf) {
        const int rb = jf * 16 + lm;
        bf16x8 bv_ = *(const bf16x8*)&VTs[rb * 128 + (((kk * 4 + quad) ^ (rb & 15)) << 3)];
        o_acc[jf] = __builtin_amdgcn_mfma_f32_16x16x32_bf16(ap, bv_, o_acc[jf], 0, 0, 0);
      }
    }
  }

  // ---- epilogue: ctx[s][d_model] scatter, bf16 ----
#pragma unroll
  for (int r = 0; r < 4; ++r) {
    float inv = 1.0f / l_run[r];
    int row = q0 + w * 16 + quad * 4 + r;
#pragma unroll
    for (int jf = 0; jf < 4; ++jf)
      ctx[((size_t)bb << 20) + ((size_t)row << 10) + (hd << 6) + jf * 16 + lm] =
          f2bf(o_acc[jf][r] * inv);
  }
}

// ---------------------------------------------------------------------------
// Weight convert + transpose: fp32 [K][N] -> bf16 [N][K]  (BT layout)
// ---------------------------------------------------------------------------
__global__ __launch_bounds__(256) void transpose_w(
    const float* __restrict__ Wq, const float* __restrict__ Wk,
    const float* __restrict__ Wv, const float* __restrict__ Wo,
    const float* __restrict__ W1, const float* __restrict__ W2,
    unsigned short* __restrict__ wqkv, unsigned short* __restrict__ wo,
    unsigned short* __restrict__ w1, unsigned short* __restrict__ w2) {
  int blk = blockIdx.x;
  int kind, local;
  if (blk < 1024) { kind = blk >> 8; local = blk & 255; }
  else if (blk < 2048) { kind = 4; local = blk - 1024; }
  else { kind = 5; local = blk - 2048; }
  const float* src;
  unsigned short* dst;
  int K, N;
  switch (kind) {
    case 0: src = Wq; dst = wqkv;                  K = 1024; N = 1024; break;
    case 1: src = Wk; dst = wqkv + 1024 * 1024;    K = 1024; N = 1024; break;
    case 2: src = Wv; dst = wqkv + 2048 * 1024;    K = 1024; N = 1024; break;
    case 3: src = Wo; dst = wo;                    K = 1024; N = 1024; break;
    case 4: src = W1; dst = w1;                    K = 1024; N = 4096; break;
    default: src = W2; dst = w2;                   K = 4096; N = 1024; break;
  }
  int tilesK = K >> 6;
  int tk = local % tilesK, tn = local / tilesK;
  int k0 = tk << 6, n0 = tn << 6;
  __shared__ float lds[64][65];
  int t = threadIdx.x;
  int rr = t >> 4, cc = (t & 15) * 4;
#pragma unroll
  for (int pp = 0; pp < 4; ++pp) {
    float4 v = *(const float4*)&src[(size_t)(k0 + rr + pp * 16) * N + n0 + cc];
    lds[rr + pp * 16][cc + 0] = v.x;
    lds[rr + pp * 16][cc + 1] = v.y;
    lds[rr + pp * 16][cc + 2] = v.z;
    lds[rr + pp * 16][cc + 3] = v.w;
  }
  __syncthreads();
#pragma unroll
  for (int pp = 0; pp < 4; ++pp) {
    int nr = rr + pp * 16;
    ushort4 o;
    o.x = f2bf(lds[cc + 0][nr]);
    o.y = f2bf(lds[cc + 1][nr]);
    o.z = f2bf(lds[cc + 2][nr]);
    o.w = f2bf(lds[cc + 3][nr]);
    *(ushort4*)&dst[(size_t)(n0 + nr) * K + k0 + cc] = o;
  }
}

// ---------------------------------------------------------------------------
// fp32 -> bf16 elementwise
// ---------------------------------------------------------------------------
__global__ __launch_bounds__(256) void cvt_bf16(const float* __restrict__ in,
                                                unsigned short* __restrict__ out) {
  int i = (blockIdx.x * 256 + threadIdx.x) * 4;
  float4 v = *(const float4*)&in[i];
  ushort4 o;
  o.x = f2bf(v.x); o.y = f2bf(v.y); o.z = f2bf(v.z); o.w = f2bf(v.w);
  *(ushort4*)&out[i] = o;
}

// ---------------------------------------------------------------------------
// LayerNorm over D=1024; in = partial0, in2 = partial1 (summed); writes
// fp32 + bf16 copies.
// ---------------------------------------------------------------------------
__global__ __launch_bounds__(256) void ln_k(const float* __restrict__ in,
                                            const float* __restrict__ in2,
                                            const float* __restrict__ g,
                                            const float* __restrict__ b,
                                            float* __restrict__ outf,
                                            unsigned short* __restrict__ outb) {
  int row = blockIdx.x;
  int t = threadIdx.x;
  const float* x = in + ((size_t)row << 10);
  const float* x2 = in2 + ((size_t)row << 10);
  float4 v = *(const float4*)&x[t * 4];
  float4 v2 = *(const float4*)&x2[t * 4];
  v.x += v2.x; v.y += v2.y; v.z += v2.z; v.w += v2.w;
  float s1 = v.x + v.y + v.z + v.w;
  float s2 = v.x * v.x + v.y * v.y + v.z * v.z + v.w * v.w;
  for (int o = 32; o > 0; o >>= 1) {
    s1 += __shfl_xor(s1, o);
    s2 += __shfl_xor(s2, o);
  }
  __shared__ float r1[4], r2[4];
  if ((t & 63) == 0) { r1[t >> 6] = s1; r2[t >> 6] = s2; }
  __syncthreads();
  s1 = r1[0] + r1[1] + r1[2] + r1[3];
  s2 = r2[0] + r2[1] + r2[2] + r2[3];
  float mean = s1 * (1.0f / 1024.0f);
  float var = s2 * (1.0f / 1024.0f) - mean * mean;
  float rstd = rsqrtf(var + 1e-12f);
  float4 gg = *(const float4*)&g[t * 4];
  float4 bb = *(const float4*)&b[t * 4];
  float o0 = (v.x - mean) * rstd * gg.x + bb.x;
  float o1 = (v.y - mean) * rstd * gg.y + bb.y;
  float o2 = (v.z - mean) * rstd * gg.z + bb.z;
  float o3 = (v.w - mean) * rstd * gg.w + bb.w;
  float4 of = make_float4(o0, o1, o2, o3);
  *(float4*)&outf[((size_t)row << 10) + t * 4] = of;
  ushort4 ob;
  ob.x = f2bf(o0); ob.y = f2bf(o1); ob.z = f2bf(o2); ob.w = f2bf(o3);
  *(ushort4*)&outb[((size_t)row << 10) + t * 4] = ob;
}

// ---------------------------------------------------------------------------
// Host driver
// ---------------------------------------------------------------------------
extern "C" void kernel_launch(void* const* d_in, const int* in_sizes, int n_in,
                              void* d_out, int out_size, void* d_ws, size_t ws_size,
                              hipStream_t stream) {
  (void)in_sizes; (void)n_in; (void)out_size; (void)ws_size;
  const float* x    = (const float*)d_in[0];
  const int*   mask = (const int*)d_in[1];
  const float* Wq   = (const float*)d_in[2];
  const float* bq   = (const float*)d_in[3];
  const float* Wk   = (const float*)d_in[4];
  const float* bk   = (const float*)d_in[5];
  const float* Wv   = (const float*)d_in[6];
  const float* bv   = (const float*)d_in[7];
  const float* Wo   = (const float*)d_in[8];
  const float* bo   = (const float*)d_in[9];
  const float* ln1g = (const float*)d_in[10];
  const float* ln1b = (const float*)d_in[11];
  const float* W1   = (const float*)d_in[12];
  const float* b1   = (const float*)d_in[13];
  const float* W2   = (const float*)d_in[14];
  const float* b2   = (const float*)d_in[15];
  const float* ln2g = (const float*)d_in[16];
  const float* ln2b = (const float*)d_in[17];
  float* out = (float*)d_out;

  char* wsp = (char*)d_ws;
  auto take = [&](size_t bytes) { char* r = wsp; wsp += bytes; return r; };
  unsigned short* wqkv = (unsigned short*)take(3072ull * 1024 * 2);
  unsigned short* wo_t = (unsigned short*)take(1024ull * 1024 * 2);
  unsigned short* w1_t = (unsigned short*)take(4096ull * 1024 * 2);
  unsigned short* w2_t = (unsigned short*)take(1024ull * 4096 * 2);
  float*          h    = (float*)take(2048ull * 1024 * 4);
  unsigned short* hbf  = (unsigned short*)take(2048ull * 1024 * 2);
  unsigned short* Qb   = (unsigned short*)take(2048ull * 1024 * 2);
  unsigned short* Kbuf = (unsigned short*)take(2048ull * 1024 * 2);
  unsigned short* VTb  = (unsigned short*)take(2048ull * 1024 * 2);
  unsigned short* ctxb = (unsigned short*)take(2048ull * 1024 * 2);
  float*          tmp  = (float*)take(2ull * 2048 * 1024 * 4);  // split-K partials
  unsigned short* ffb  = (unsigned short*)take(2048ull * 4096 * 2);
  const long long TMPZ = 2048ll * 1024;

  cvt_bf16<<<2048, 256, 0, stream>>>(x, hbf);

  for (int l = 0; l < 4; ++l) {
    transpose_w<<<3072, 256, 0, stream>>>(
        Wq + (size_t)l * 1048576, Wk + (size_t)l * 1048576,
        Wv + (size_t)l * 1048576, Wo + (size_t)l * 1048576,
        W1 + (size_t)l * 4194304, W2 + (size_t)l * 4194304,
        wqkv, wo_t, w1_t, w2_t);

    // QKV projection: [2048 x 3072], 64x128 tile -> 768 blocks (3/CU)
    {
      EpParams p{};
      p.bias = bq + l * 1024; p.bias2 = bk + l * 1024; p.bias3 = bv + l * 1024;
      p.outb = Qb; p.outb2 = Kbuf; p.outb3 = VTb;
      gemm_bt<64, 128, 2, 2, 2, 4, 0><<<dim3(24, 32, 1), 256, 0, stream>>>(
          hbf, wqkv, 1024, 16, 0, 0, p);
    }

    // Fused attention: 16 q-tiles x 32 pairs = 512 blocks (2/CU)
    flash_attn<<<dim3(16, 32), 256, 0, stream>>>(Qb, Kbuf, VTb, mask, ctxb);

    // O projection + bias + residual, split-K=2 -> 512 blocks
    {
      EpParams p{};
      p.bias = bo + l * 1024; p.res = (l == 0 ? x : h);
      p.outf = tmp; p.strideCz = TMPZ; p.ldC = 1024;
      gemm_bt<128, 64, 2, 2, 4, 2, 3><<<dim3(16, 16, 2), 256, 0, stream>>>(
          ctxb, wo_t, 1024, 8, 512, 512, p);
    }
    ln_k<<<2048, 256, 0, stream>>>(tmp, tmp + TMPZ,
                                   ln1g + l * 1024, ln1b + l * 1024, h, hbf);

    // FFN1 + GELU: 64x128 tile -> 1024 blocks (4/CU)
    {
      EpParams p{};
      p.bias = b1 + l * 4096; p.outb = ffb; p.ldC = 4096;
      gemm_bt<64, 128, 2, 2, 2, 4, 4><<<dim3(32, 32, 1), 256, 0, stream>>>(
          hbf, w1_t, 1024, 16, 0, 0, p);
    }
    // FFN2 + bias + residual, split-K=2 -> 512 blocks
    {
      EpParams p{};
      p.bias = b2 + l * 1024; p.res = h;
      p.outf = tmp; p.strideCz = TMPZ; p.ldC = 1024;
      gemm_bt<128, 64, 2, 2, 4, 2, 3><<<dim3(16, 16, 2), 256, 0, stream>>>(
          ffb, w2_t, 4096, 32, 2048, 2048, p);
    }
    ln_k<<<2048, 256, 0, stream>>>(tmp, tmp + TMPZ,
                                   ln2g + l * 1024, ln2b + l * 1024,
                                   (l == 3 ? out : h), hbf);
  }
}

// Round 5
// 819.230 us; speedup vs baseline: 2.0768x; 1.0063x over previous
//
#include <hip/hip_runtime.h>
#include <cstdint>
#include <cstddef>

// ---------------------------------------------------------------------------
// Types
// ---------------------------------------------------------------------------
using bf16x8 = __attribute__((ext_vector_type(8))) short;
using f32x4  = __attribute__((ext_vector_type(4))) float;

__device__ __forceinline__ unsigned short f2bf(float f) {
  unsigned int u = __builtin_bit_cast(unsigned int, f);
  u += 0x7fffu + ((u >> 16) & 1u);
  return (unsigned short)(u >> 16);
}
__device__ __forceinline__ float bf2f(unsigned short h) {
  unsigned int u = ((unsigned int)h) << 16;
  return __builtin_bit_cast(float, u);
}

// async global->LDS 16B per lane. LDS dest must be wave-uniform-base + lane*16.
__device__ __forceinline__ void async_cp16(const void* g, void* l) {
  __builtin_amdgcn_global_load_lds(
      (__attribute__((address_space(1))) void*)(g),
      (__attribute__((address_space(3))) void*)(l), 16, 0, 0);
}

// ---------------------------------------------------------------------------
// Epilogue params
// ---------------------------------------------------------------------------
struct EpParams {
  const float* bias;    // col bias
  const float* bias2;   // (qkv) k bias
  const float* bias3;   // (qkv) v bias
  const float* res;     // residual fp32 [M][ldC]
  float* outf;          // fp32 out
  unsigned short* outb; // bf16 out
  unsigned short* outb2;
  unsigned short* outb3;
  long long strideCz;   // elements
  int ldC;
  int pair_base;
};

// EP: 0=QKV scatter, 3=bias+residual f32 (split-K aware: z0 adds bias+res,
// z>0 writes raw partial to outf+z*strideCz), 4=gelu bf16
// LDS XOR swizzle: LDS slot (row, chunk) holds global 16B-chunk (chunk ^ (row&7)).
template <int BM, int BN, int WGM, int WGN, int FI, int FJ, int EP>
__global__ __launch_bounds__(256, 2) void gemm_bt(
    const unsigned short* __restrict__ A, const unsigned short* __restrict__ B,
    int K, int kTiles, long long strideAz, long long strideBz, EpParams p) {
  __shared__ alignas(16) unsigned short As[BM * 64];
  __shared__ alignas(16) unsigned short Bs[BN * 64];
  const int t = threadIdx.x;
  const int lane = t & 63;
  const int w = t >> 6;
  const int wr = w / WGN, wc = w % WGN;
  const int lm = lane & 15, quad = lane >> 4;
  const int m0 = blockIdx.y * BM, n0 = blockIdx.x * BN;
  const int bz = blockIdx.z;
  A += (long long)bz * strideAz;
  B += (long long)bz * strideBz;

  f32x4 acc[FI][FJ] = {};

  const int rowA = t >> 3;                       // 0..31 within a staging step
  const int colSw = ((t & 7) ^ (rowA & 7)) * 8;  // swizzled source column

  for (int kt = 0; kt < kTiles; ++kt) {
    const unsigned short* ga = A + (size_t)(m0 + rowA) * K + kt * 64 + colSw;
    const unsigned short* gb = B + (size_t)(n0 + rowA) * K + kt * 64 + colSw;
#pragma unroll
    for (int s = 0; s < BM / 32; ++s)
      async_cp16(ga + (size_t)s * 32 * K, &As[s * 2048 + t * 8]);
#pragma unroll
    for (int s = 0; s < BN / 32; ++s)
      async_cp16(gb + (size_t)s * 32 * K, &Bs[s * 2048 + t * 8]);
    __syncthreads();
#pragma unroll
    for (int ks = 0; ks < 2; ++ks) {
      bf16x8 af[FI], bfr[FJ];
#pragma unroll
      for (int i = 0; i < FI; ++i) {
        int ra = wr * FI * 16 + i * 16 + lm;
        af[i] = *(const bf16x8*)&As[ra * 64 + (((ks * 4 + quad) ^ (ra & 7)) << 3)];
      }
#pragma unroll
      for (int j = 0; j < FJ; ++j) {
        int rb = wc * FJ * 16 + j * 16 + lm;
        bfr[j] = *(const bf16x8*)&Bs[rb * 64 + (((ks * 4 + quad) ^ (rb & 7)) << 3)];
      }
#pragma unroll
      for (int i = 0; i < FI; ++i)
#pragma unroll
        for (int j = 0; j < FJ; ++j)
          acc[i][j] = __builtin_amdgcn_mfma_f32_16x16x32_bf16(af[i], bfr[j], acc[i][j], 0, 0, 0);
    }
    __syncthreads();
  }

#pragma unroll
  for (int i = 0; i < FI; ++i) {
#pragma unroll
    for (int j = 0; j < FJ; ++j) {
#pragma unroll
      for (int r = 0; r < 4; ++r) {
        int row = m0 + wr * FI * 16 + i * 16 + quad * 4 + r;
        int col = n0 + wc * FJ * 16 + j * 16 + lm;
        float v = acc[i][j][r];
        if constexpr (EP == 0) {
          int bb = row >> 10, s = row & 1023;
          if (col < 1024) {
            float q = (v + p.bias[col]) * 0.125f;
            int hd = col >> 6, dh = col & 63;
            p.outb[((size_t)(bb * 16 + hd) << 16) + (s << 6) + dh] = f2bf(q);
          } else if (col < 2048) {
            int c2 = col - 1024;
            float kk = v + p.bias2[c2];
            int hd = c2 >> 6, dh = c2 & 63;
            p.outb2[((size_t)(bb * 16 + hd) << 16) + (s << 6) + dh] = f2bf(kk);
          } else {
            int c3 = col - 2048;
            float vv = v + p.bias3[c3];
            int hd = c3 >> 6, dh = c3 & 63;
            p.outb3[((size_t)(bb * 16 + hd) << 16) + ((size_t)dh << 10) + s] = f2bf(vv);
          }
        } else if constexpr (EP == 3) {
          size_t idx = (size_t)row * p.ldC + col;
          float add = (bz == 0) ? (p.bias[col] + p.res[idx]) : 0.0f;
          p.outf[(long long)bz * p.strideCz + idx] = v + add;
        } else if constexpr (EP == 4) {
          float val = v + p.bias[col];
          float g = 0.5f * val * (1.0f + erff(val * 0.70710678118654752f));
          p.outb[(size_t)row * p.ldC + col] = f2bf(g);
        }
      }
    }
  }
}

// ---------------------------------------------------------------------------
// Fused flash attention (prefill). One block = (64-row Q-tile, pair).
// Wave grid 4x1: wave w owns q-rows w*16..w*16+15 entirely -> softmax
// reductions are 16-lane shuffles; P round-trips LDS per-wave (no barrier).
// Q pre-scaled by 1/8 at QKV epilogue. K-tile = 128 keys.
// ---------------------------------------------------------------------------
__global__ __launch_bounds__(256, 2) void flash_attn(
    const unsigned short* __restrict__ Qb, const unsigned short* __restrict__ Kb,
    const unsigned short* __restrict__ VTb, const int* __restrict__ mask,
    unsigned short* __restrict__ ctx) {
  __shared__ alignas(16) unsigned short Qs[64 * 64];
  __shared__ alignas(16) unsigned short Ks[128 * 64];
  __shared__ alignas(16) unsigned short VTs[64 * 128];
  __shared__ alignas(16) unsigned short Ps[64 * 128];
  const int t = threadIdx.x;
  const int lane = t & 63;
  const int w = t >> 6;
  const int lm = lane & 15, quad = lane >> 4;
  const int pair = blockIdx.y;
  const int q0 = blockIdx.x * 64;
  const int bb = pair >> 4, hd = pair & 15;
  const unsigned short* Qp = Qb + ((size_t)pair << 16);
  const unsigned short* Kp = Kb + ((size_t)pair << 16);
  const unsigned short* Vp = VTb + ((size_t)pair << 16);
  const int* mrow = mask + (bb << 10);

  // stage Q (64 rows x 64), XOR-swizzled chunks
  {
    const int rowA = t >> 3;
    const int c = t & 7;
#pragma unroll
    for (int s = 0; s < 2; ++s) {
      int row = s * 32 + rowA;
      async_cp16(Qp + (size_t)(q0 + row) * 64 + ((c ^ (row & 7)) << 3),
                 &Qs[s * 2048 + t * 8]);
    }
  }

  f32x4 o_acc[4] = {};
  float m_run[4], l_run[4];
#pragma unroll
  for (int r = 0; r < 4; ++r) { m_run[r] = -3e38f; l_run[r] = 0.f; }

  for (int k0 = 0; k0 < 1024; k0 += 128) {
    __syncthreads();  // previous iteration done reading Ks/VTs (and Q ready)
    {
      const int rowA = t >> 3;
      const int c = t & 7;
#pragma unroll
      for (int s = 0; s < 4; ++s) {
        int row = s * 32 + rowA;
        async_cp16(Kp + (size_t)(k0 + row) * 64 + ((c ^ (row & 7)) << 3),
                   &Ks[s * 2048 + t * 8]);
      }
      const int rowV = t >> 4;
      const int cv = t & 15;
#pragma unroll
      for (int s = 0; s < 4; ++s) {
        int row = s * 16 + rowV;
        async_cp16(Vp + (size_t)row * 1024 + k0 + ((cv ^ (row & 15)) << 3),
                   &VTs[s * 2048 + t * 8]);
      }
    }
    int mv[8];
#pragma unroll
    for (int j = 0; j < 8; ++j) mv[j] = mrow[k0 + j * 16 + lm];
    __syncthreads();  // staged tiles visible

    // ---- QK^T: wave w -> 16 q-rows x 128 keys ----
    f32x4 s_acc[8] = {};
    {
      const int ra = w * 16 + lm;
      bf16x8 aq[2];
#pragma unroll
      for (int ks = 0; ks < 2; ++ks)
        aq[ks] = *(const bf16x8*)&Qs[ra * 64 + (((ks * 4 + quad) ^ (ra & 7)) << 3)];
#pragma unroll
      for (int j = 0; j < 8; ++j) {
        const int rb = j * 16 + lm;
#pragma unroll
        for (int ks = 0; ks < 2; ++ks) {
          bf16x8 bk_ = *(const bf16x8*)&Ks[rb * 64 + (((ks * 4 + quad) ^ (rb & 7)) << 3)];
          s_acc[j] = __builtin_amdgcn_mfma_f32_16x16x32_bf16(aq[ks], bk_, s_acc[j], 0, 0, 0);
        }
      }
    }

    // ---- mask + online softmax (rows = quad*4+r, cols = lm+16j) ----
    float mt[4];
#pragma unroll
    for (int r = 0; r < 4; ++r) mt[r] = -3e38f;
#pragma unroll
    for (int j = 0; j < 8; ++j)
#pragma unroll
      for (int r = 0; r < 4; ++r) {
        float sv = mv[j] ? s_acc[j][r] : -1e30f;
        s_acc[j][r] = sv;
        mt[r] = fmaxf(mt[r], sv);
      }
#pragma unroll
    for (int r = 0; r < 4; ++r)
#pragma unroll
      for (int off = 1; off < 16; off <<= 1)
        mt[r] = fmaxf(mt[r], __shfl_xor(mt[r], off));
    float alpha[4], lt[4];
#pragma unroll
    for (int r = 0; r < 4; ++r) {
      float mn = fmaxf(m_run[r], mt[r]);
      alpha[r] = __expf(m_run[r] - mn);
      m_run[r] = mn;
      lt[r] = 0.f;
    }
#pragma unroll
    for (int j = 0; j < 8; ++j)
#pragma unroll
      for (int r = 0; r < 4; ++r) {
        float pv = __expf(s_acc[j][r] - m_run[r]);
        s_acc[j][r] = pv;
        lt[r] += pv;
      }
#pragma unroll
    for (int r = 0; r < 4; ++r) {
#pragma unroll
      for (int off = 1; off < 16; off <<= 1) lt[r] += __shfl_xor(lt[r], off);
      l_run[r] = l_run[r] * alpha[r] + lt[r];
    }
#pragma unroll
    for (int jf = 0; jf < 4; ++jf)
#pragma unroll
      for (int r = 0; r < 4; ++r) o_acc[jf][r] *= alpha[r];

    // ---- P: C-layout regs -> LDS A-layout (per-wave rows, swizzled) ----
#pragma unroll
    for (int j = 0; j < 8; ++j) {
      const int chunk = 2 * j + (lm >> 3);
#pragma unroll
      for (int r = 0; r < 4; ++r) {
        const int row = w * 16 + quad * 4 + r;
        Ps[row * 128 + ((chunk ^ (row & 15)) << 3) + (lm & 7)] = f2bf(s_acc[j][r]);
      }
    }

    // ---- PV: wave w -> 16 rows x 64 dh, K=128 ----
    const int ra = w * 16 + lm;
#pragma unroll
    for (int kk = 0; kk < 4; ++kk) {
      bf16x8 ap = *(const bf16x8*)&Ps[ra * 128 + (((kk * 4 + quad) ^ (ra & 15)) << 3)];
#pragma unroll
      for (int jf = 0; jf < 4; ++jf) {
        const int rb = jf * 16 + lm;
        bf16x8 bv_ = *(const bf16x8*)&VTs[rb * 128 + (((kk * 4 + quad) ^ (rb & 15)) << 3)];
        o_acc[jf] = __builtin_amdgcn_mfma_f32_16x16x32_bf16(ap, bv_, o_acc[jf], 0, 0, 0);
      }
    }
  }

  // ---- epilogue: ctx[s][d_model] scatter, bf16 ----
#pragma unroll
  for (int r = 0; r < 4; ++r) {
    float inv = 1.0f / l_run[r];
    int row = q0 + w * 16 + quad * 4 + r;
#pragma unroll
    for (int jf = 0; jf < 4; ++jf)
      ctx[((size_t)bb << 20) + ((size_t)row << 10) + (hd << 6) + jf * 16 + lm] =
          f2bf(o_acc[jf][r] * inv);
  }
}

// ---------------------------------------------------------------------------
// Weight convert + transpose: fp32 [K][N] -> bf16 [N][K]  (BT layout)
// ---------------------------------------------------------------------------
__global__ __launch_bounds__(256) void transpose_w(
    const float* __restrict__ Wq, const float* __restrict__ Wk,
    const float* __restrict__ Wv, const float* __restrict__ Wo,
    const float* __restrict__ W1, const float* __restrict__ W2,
    unsigned short* __restrict__ wqkv, unsigned short* __restrict__ wo,
    unsigned short* __restrict__ w1, unsigned short* __restrict__ w2) {
  int blk = blockIdx.x;
  int kind, local;
  if (blk < 1024) { kind = blk >> 8; local = blk & 255; }
  else if (blk < 2048) { kind = 4; local = blk - 1024; }
  else { kind = 5; local = blk - 2048; }
  const float* src;
  unsigned short* dst;
  int K, N;
  switch (kind) {
    case 0: src = Wq; dst = wqkv;                  K = 1024; N = 1024; break;
    case 1: src = Wk; dst = wqkv + 1024 * 1024;    K = 1024; N = 1024; break;
    case 2: src = Wv; dst = wqkv + 2048 * 1024;    K = 1024; N = 1024; break;
    case 3: src = Wo; dst = wo;                    K = 1024; N = 1024; break;
    case 4: src = W1; dst = w1;                    K = 1024; N = 4096; break;
    default: src = W2; dst = w2;                   K = 4096; N = 1024; break;
  }
  int tilesK = K >> 6;
  int tk = local % tilesK, tn = local / tilesK;
  int k0 = tk << 6, n0 = tn << 6;
  __shared__ float lds[64][65];
  int t = threadIdx.x;
  int rr = t >> 4, cc = (t & 15) * 4;
#pragma unroll
  for (int pp = 0; pp < 4; ++pp) {
    float4 v = *(const float4*)&src[(size_t)(k0 + rr + pp * 16) * N + n0 + cc];
    lds[rr + pp * 16][cc + 0] = v.x;
    lds[rr + pp * 16][cc + 1] = v.y;
    lds[rr + pp * 16][cc + 2] = v.z;
    lds[rr + pp * 16][cc + 3] = v.w;
  }
  __syncthreads();
#pragma unroll
  for (int pp = 0; pp < 4; ++pp) {
    int nr = rr + pp * 16;
    ushort4 o;
    o.x = f2bf(lds[cc + 0][nr]);
    o.y = f2bf(lds[cc + 1][nr]);
    o.z = f2bf(lds[cc + 2][nr]);
    o.w = f2bf(lds[cc + 3][nr]);
    *(ushort4*)&dst[(size_t)(n0 + nr) * K + k0 + cc] = o;
  }
}

// ---------------------------------------------------------------------------
// fp32 -> bf16 elementwise
// ---------------------------------------------------------------------------
__global__ __launch_bounds__(256) void cvt_bf16(const float* __restrict__ in,
                                                unsigned short* __restrict__ out) {
  int i = (blockIdx.x * 256 + threadIdx.x) * 4;
  float4 v = *(const float4*)&in[i];
  ushort4 o;
  o.x = f2bf(v.x); o.y = f2bf(v.y); o.z = f2bf(v.z); o.w = f2bf(v.w);
  *(ushort4*)&out[i] = o;
}

// ---------------------------------------------------------------------------
// LayerNorm over D=1024; sums npart split-K partials (stride strideZ);
// writes fp32 + bf16 copies.
// ---------------------------------------------------------------------------
__global__ __launch_bounds__(256) void ln_k(const float* __restrict__ in,
                                            int npart, long long strideZ,
                                            const float* __restrict__ g,
                                            const float* __restrict__ b,
                                            float* __restrict__ outf,
                                            unsigned short* __restrict__ outb) {
  int row = blockIdx.x;
  int t = threadIdx.x;
  const float* x = in + ((size_t)row << 10);
  float4 v = *(const float4*)&x[t * 4];
  for (int z = 1; z < npart; ++z) {
    float4 v2 = *(const float4*)&x[(size_t)z * strideZ + t * 4];
    v.x += v2.x; v.y += v2.y; v.z += v2.z; v.w += v2.w;
  }
  float s1 = v.x + v.y + v.z + v.w;
  float s2 = v.x * v.x + v.y * v.y + v.z * v.z + v.w * v.w;
  for (int o = 32; o > 0; o >>= 1) {
    s1 += __shfl_xor(s1, o);
    s2 += __shfl_xor(s2, o);
  }
  __shared__ float r1[4], r2[4];
  if ((t & 63) == 0) { r1[t >> 6] = s1; r2[t >> 6] = s2; }
  __syncthreads();
  s1 = r1[0] + r1[1] + r1[2] + r1[3];
  s2 = r2[0] + r2[1] + r2[2] + r2[3];
  float mean = s1 * (1.0f / 1024.0f);
  float var = s2 * (1.0f / 1024.0f) - mean * mean;
  float rstd = rsqrtf(var + 1e-12f);
  float4 gg = *(const float4*)&g[t * 4];
  float4 bb = *(const float4*)&b[t * 4];
  float o0 = (v.x - mean) * rstd * gg.x + bb.x;
  float o1 = (v.y - mean) * rstd * gg.y + bb.y;
  float o2 = (v.z - mean) * rstd * gg.z + bb.z;
  float o3 = (v.w - mean) * rstd * gg.w + bb.w;
  float4 of = make_float4(o0, o1, o2, o3);
  *(float4*)&outf[((size_t)row << 10) + t * 4] = of;
  ushort4 ob;
  ob.x = f2bf(o0); ob.y = f2bf(o1); ob.z = f2bf(o2); ob.w = f2bf(o3);
  *(ushort4*)&outb[((size_t)row << 10) + t * 4] = ob;
}

// ---------------------------------------------------------------------------
// Host driver
// ---------------------------------------------------------------------------
extern "C" void kernel_launch(void* const* d_in, const int* in_sizes, int n_in,
                              void* d_out, int out_size, void* d_ws, size_t ws_size,
                              hipStream_t stream) {
  (void)in_sizes; (void)n_in; (void)out_size; (void)ws_size;
  const float* x    = (const float*)d_in[0];
  const int*   mask = (const int*)d_in[1];
  const float* Wq   = (const float*)d_in[2];
  const float* bq   = (const float*)d_in[3];
  const float* Wk   = (const float*)d_in[4];
  const float* bk   = (const float*)d_in[5];
  const float* Wv   = (const float*)d_in[6];
  const float* bv   = (const float*)d_in[7];
  const float* Wo   = (const float*)d_in[8];
  const float* bo   = (const float*)d_in[9];
  const float* ln1g = (const float*)d_in[10];
  const float* ln1b = (const float*)d_in[11];
  const float* W1   = (const float*)d_in[12];
  const float* b1   = (const float*)d_in[13];
  const float* W2   = (const float*)d_in[14];
  const float* b2   = (const float*)d_in[15];
  const float* ln2g = (const float*)d_in[16];
  const float* ln2b = (const float*)d_in[17];
  float* out = (float*)d_out;

  char* wsp = (char*)d_ws;
  auto take = [&](size_t bytes) { char* r = wsp; wsp += bytes; return r; };
  unsigned short* wqkv = (unsigned short*)take(3072ull * 1024 * 2);
  unsigned short* wo_t = (unsigned short*)take(1024ull * 1024 * 2);
  unsigned short* w1_t = (unsigned short*)take(4096ull * 1024 * 2);
  unsigned short* w2_t = (unsigned short*)take(1024ull * 4096 * 2);
  float*          h    = (float*)take(2048ull * 1024 * 4);
  unsigned short* hbf  = (unsigned short*)take(2048ull * 1024 * 2);
  unsigned short* Qb   = (unsigned short*)take(2048ull * 1024 * 2);
  unsigned short* Kbuf = (unsigned short*)take(2048ull * 1024 * 2);
  unsigned short* VTb  = (unsigned short*)take(2048ull * 1024 * 2);
  unsigned short* ctxb = (unsigned short*)take(2048ull * 1024 * 2);
  float*          tmp  = (float*)take(4ull * 2048 * 1024 * 4);  // split-K partials (up to 4)
  unsigned short* ffb  = (unsigned short*)take(2048ull * 4096 * 2);
  const long long TMPZ = 2048ll * 1024;

  cvt_bf16<<<2048, 256, 0, stream>>>(x, hbf);

  for (int l = 0; l < 4; ++l) {
    transpose_w<<<3072, 256, 0, stream>>>(
        Wq + (size_t)l * 1048576, Wk + (size_t)l * 1048576,
        Wv + (size_t)l * 1048576, Wo + (size_t)l * 1048576,
        W1 + (size_t)l * 4194304, W2 + (size_t)l * 4194304,
        wqkv, wo_t, w1_t, w2_t);

    // QKV projection: [2048 x 3072], 64x128 tile -> 768 blocks (3/CU)
    {
      EpParams p{};
      p.bias = bq + l * 1024; p.bias2 = bk + l * 1024; p.bias3 = bv + l * 1024;
      p.outb = Qb; p.outb2 = Kbuf; p.outb3 = VTb;
      gemm_bt<64, 128, 2, 2, 2, 4, 0><<<dim3(24, 32, 1), 256, 0, stream>>>(
          hbf, wqkv, 1024, 16, 0, 0, p);
    }

    // Fused attention: 16 q-tiles x 32 pairs = 512 blocks (2/CU)
    flash_attn<<<dim3(16, 32), 256, 0, stream>>>(Qb, Kbuf, VTb, mask, ctxb);

    // O projection + bias + residual, split-K=2 -> 512 blocks
    {
      EpParams p{};
      p.bias = bo + l * 1024; p.res = (l == 0 ? x : h);
      p.outf = tmp; p.strideCz = TMPZ; p.ldC = 1024;
      gemm_bt<128, 64, 2, 2, 4, 2, 3><<<dim3(16, 16, 2), 256, 0, stream>>>(
          ctxb, wo_t, 1024, 8, 512, 512, p);
    }
    ln_k<<<2048, 256, 0, stream>>>(tmp, 2, TMPZ,
                                   ln1g + l * 1024, ln1b + l * 1024, h, hbf);

    // FFN1 + GELU: 128x128 tile -> 512 blocks (2/CU)
    {
      EpParams p{};
      p.bias = b1 + l * 4096; p.outb = ffb; p.ldC = 4096;
      gemm_bt<128, 128, 2, 2, 4, 4, 4><<<dim3(32, 16, 1), 256, 0, stream>>>(
          hbf, w1_t, 1024, 16, 0, 0, p);
    }
    // FFN2 + bias + residual, split-K=4 -> 1024 blocks (4/CU)
    {
      EpParams p{};
      p.bias = b2 + l * 1024; p.res = h;
      p.outf = tmp; p.strideCz = TMPZ; p.ldC = 1024;
      gemm_bt<128, 64, 2, 2, 4, 2, 3><<<dim3(16, 16, 4), 256, 0, stream>>>(
          ffb, w2_t, 4096, 16, 1024, 1024, p);
    }
    ln_k<<<2048, 256, 0, stream>>>(tmp, 4, TMPZ,
                                   ln2g + l * 1024, ln2b + l * 1024,
                                   (l == 3 ? out : h), hbf);
  }
}